// Round 5
// baseline (1415.903 us; speedup 1.0000x reference)
//
#include <hip/hip_runtime.h>
#include <hip/hip_fp16.h>

#define TN 64
#define BN 2048
#define G 8
#define NBLK (BN / G)   // 256 blocks x 512 threads, 1 block/CU, SINGLE round

// KK = -2/ln2: pre-scales attention-tanh inputs so e-loop computes
// sigma(2x) = 1/(1 + 2^(KK*x)) with no per-element multiply.
#define KK (-2.88539008f)

typedef _Float16 h2v __attribute__((ext_vector_type(2)));
typedef _Float16 half8 __attribute__((ext_vector_type(8)));
typedef float float4v __attribute__((ext_vector_type(4)));

union FU {
    uint4 u;
    half8 h8;
    h2v hv[4];
    __half2 h2[4];
    _Float16 f16[8];
};
union H2U { __half2 h; h2v v; };

#define LAUNDER4(v) asm volatile("" : "+v"((v).x), "+v"((v).y), "+v"((v).z), "+v"((v).w))

__device__ __forceinline__ float fast_sigmoid(float x) {
    return __builtin_amdgcn_rcpf(1.f + __expf(-x));
}
__device__ __forceinline__ float fast_tanhf(float x) {
    return fmaf(2.f, fast_sigmoid(2.f * x), -1.f);
}
__device__ __forceinline__ float fdot2f(__half2 a, __half2 b, float c) {
    H2U ua; ua.h = a; H2U ub; ub.h = b;
    return __builtin_amdgcn_fdot2(ua.v, ub.v, c, false);
}
// packed fp16 sigmoid(2x) where xs = KK*x is PRE-SCALED (KK folded into HWh/W1m):
// tv = 2^xs = e^{-2x}; r = 1/(1+tv). tanh(x) = 2r-1 is folded into softmax
// shift-invariance (e-loop accumulates 2*w2*r via pre-doubled w2h).
__device__ __forceinline__ __half2 sig2(__half2 xs, __half2 one2) {
    __half2 tv = h2exp2(xs);
    return h2rcp(__hadd2(tv, one2));
}

// wave64 sum via DPP (row_shr 1/2/4/8 + row_bcast15/31), result broadcast from
// lane 63. ~80 cyc vs ~250+ for 6 dependent ds_bpermute shuffles.
__device__ __forceinline__ float wave_sum64(float x) {
    union FI { float f; int i; };
    FI a, b; a.f = x;
    b.i = __builtin_amdgcn_update_dpp(0, a.i, 0x111, 0xf, 0xf, true); a.f += b.f;
    b.i = __builtin_amdgcn_update_dpp(0, a.i, 0x112, 0xf, 0xf, true); a.f += b.f;
    b.i = __builtin_amdgcn_update_dpp(0, a.i, 0x114, 0xf, 0xf, true); a.f += b.f;
    b.i = __builtin_amdgcn_update_dpp(0, a.i, 0x118, 0xf, 0xf, true); a.f += b.f;
    b.i = __builtin_amdgcn_update_dpp(0, a.i, 0x142, 0xf, 0xf, true); a.f += b.f;
    b.i = __builtin_amdgcn_update_dpp(0, a.i, 0x143, 0xf, 0xf, true); a.f += b.f;
    FI r; r.i = __builtin_amdgcn_readlane(a.i, 63);
    return r.f;
}

// dc swizzled offset (halves): chunk c of row g at slot (c&16)|((c&15)^g)
__device__ __forceinline__ int dc_off(int g, int e) {
    int c = e >> 3;
    int slot = (c & 16) | ((c & 15) ^ (g & 15));
    return g * 256 + slot * 8 + (e & 7);
}

// ---- HW[b,t,f] = KK * (H[b,t,:] @ W1[256:384,:] + b1), fp16 linear [b*T+t][128]
__global__ __launch_bounds__(256) void prep_hw(
    const float* __restrict__ H, const float* __restrict__ W1,
    const float* __restrict__ b1, __half* __restrict__ HWh) {
    __shared__ float sH[16 * 128];
    const int i = threadIdx.x;
    const long r0 = (long)blockIdx.x * 16;
    #pragma unroll
    for (int u = 0; u < 8; ++u) sH[u * 256 + i] = H[r0 * 128 + u * 256 + i];
    __syncthreads();
    const int f = i & 127;
    const int half_ = i >> 7;
    float acc[8];
    float bb = b1[f];
    #pragma unroll
    for (int u = 0; u < 8; ++u) acc[u] = bb;
    #pragma unroll 4
    for (int h = 0; h < 128; ++h) {
        float wv = W1[(256 + h) * 128 + f];
        #pragma unroll
        for (int u = 0; u < 8; ++u)
            acc[u] = fmaf(sH[(half_ + 2 * u) * 128 + h], wv, acc[u]);
    }
    #pragma unroll
    for (int u = 0; u < 8; ++u)
        HWh[(r0 + half_ + 2 * u) * 128 + f] = __float2half(KK * acc[u]);
}

// ---- HhT[b][f][t] = fp16(H[b][t][f])
__global__ __launch_bounds__(256) void prep_ht(
    const float* __restrict__ H, __half* __restrict__ HhT) {
    __shared__ __half sh[64 * 128];
    const int b = blockIdx.x, i = threadIdx.x;
    #pragma unroll
    for (int u = 0; u < 32; ++u) {
        int idx = u * 256 + i;
        sh[idx] = __float2half(H[(long)b * 8192 + idx]);
    }
    __syncthreads();
    const int f = i >> 1, t0 = (i & 1) * 32;
    __half* ob = HhT + (long)b * 8192 + (long)i * 32;
    #pragma unroll
    for (int k = 0; k < 32; ++k) ob[k] = sh[(t0 + k) * 128 + f];
}

// ---- W1m: KK * W1[0:256][:] in MFMA B-frag layout (frag fi = w*8+kt)
__global__ __launch_bounds__(256) void prep_w1m(
    const float* __restrict__ W1, __half* __restrict__ W1m) {
    int tid = blockIdx.x * 256 + threadIdx.x;   // 32768
    int fi = tid >> 9, rem = tid & 511, l = rem >> 3, j = rem & 7;
    int w = fi >> 3, kt = fi & 7;
    int row = kt * 32 + (l >> 4) * 8 + j;
    int col = w * 16 + (l & 15);
    W1m[tid] = __float2half(KK * W1[row * 128 + col]);
}

// ---- WTm: Whh^T in MFMA B-frag layout (frag fi = nt*4+kt)
__global__ __launch_bounds__(256) void prep_wtm(
    const float* __restrict__ Whh, __half* __restrict__ WTm) {
    int tid = blockIdx.x * 256 + threadIdx.x;   // 65536
    int fi = tid >> 9, rem = tid & 511, l = rem >> 3, j = rem & 7;
    int nt = fi >> 2, kt = fi & 3;
    int k = kt * 32 + (l >> 4) * 8 + j;
    int n = nt * 16 + (l & 15);
    WTm[tid] = __float2half(Whh[n * 128 + k]);
}

struct SMem {
    __half ht[G * 128 * 64];   // 131072 B  H^T tile [g][f][t], granule-XOR swizzle
    __half dc[G * 256];        //   4096 B  dc_off swizzle
    float sg[G * 512];         //  16384 B  gates [g][512]
    __half spH[G * 128];       //   2048 B  p fp16 [g][128] (KK-scaled)
    __half ctxH[G * 128];      //   2048 B  ctx fp16 [g][128] (written final step only)
    __half beta[G * 64];       //   1024 B  fp16 beta [g][64]
    __half w2h[128];           //    256 B  (pre-doubled: 2*W2)
    float sY[G * 64];          //   2048 B
};                             // 158976 B total, 1 block/CU

__global__ __launch_bounds__(512, 2) void decoder_scan(
    const float* __restrict__ Y, const float* __restrict__ W2,
    const float* __restrict__ Wih, const float* __restrict__ bih,
    const float* __restrict__ bhh, const float* __restrict__ fcW,
    const float* __restrict__ fcb, const float* __restrict__ fcfW,
    const float* __restrict__ fcfb,
    const __half* __restrict__ HWh, const __half* __restrict__ HhT,
    const uint4* __restrict__ W1m4, const uint4* __restrict__ WTm4,
    float* __restrict__ out) {

    __shared__ SMem sm;

    const int tid = threadIdx.x;
    const int bbase = blockIdx.x * G;
    const int lane = tid & 63;
    const int wv = tid >> 6;            // wave id == batch-group g
    const int g = wv;

    // ---- init ----
    // HW[g][t=lane][0..127] -> laundered registers (64 VGPR)
    uint4 hwr[16];
    {
        const uint4* src = (const uint4*)(HWh + (((long)(bbase + g) * TN + lane) * 128));
        #pragma unroll
        for (int u = 0; u < 16; ++u) { hwr[u] = src[u]; LAUNDER4(hwr[u]); }
    }
    // H^T tile -> LDS with granule swizzle (granule u of row at u ^ (f&7))
    {
        const uint4* src = (const uint4*)(HhT + (long)bbase * 8192);
        #pragma unroll
        for (int u = 0; u < 16; ++u) {
            int idx = u * 512 + tid;             // granule 0..8191
            int f7 = (idx >> 3) & 7;
            ((uint4*)sm.ht)[(idx & ~7) | ((idx & 7) ^ f7)] = src[idx];
        }
    }
    // W1 B-frags (8 = 32 regs), WhhT B-frags (16 = 64 regs), laundered (AGPR-ok)
    uint4 w1f[8];
    #pragma unroll
    for (int kt = 0; kt < 8; ++kt) {
        w1f[kt] = W1m4[(size_t)(wv * 8 + kt) * 64 + lane];
        LAUNDER4(w1f[kt]);
    }
    uint4 wtf[16];
    #pragma unroll
    for (int q = 0; q < 16; ++q) {
        wtf[q] = WTm4[(size_t)(wv * 16 + q) * 64 + lane];
        LAUNDER4(wtf[q]);
    }
    ((unsigned*)sm.dc)[tid] = 0u;
    ((unsigned*)sm.dc)[512 + tid] = 0u;
    if (tid < 128) sm.w2h[tid] = __float2half(2.f * W2[tid]);   // fold softmax 2x
    sm.sY[tid] = Y[(long)bbase * TN + tid];
    float c0 = 0.f, c1 = 0.f;
    float wihA[4], wihB[4], bsA[4], bsB[4];
    #pragma unroll
    for (int q = 0; q < 4; ++q) {
        wihA[q] = Wih[q * 128 + lane];
        wihB[q] = Wih[q * 128 + 64 + lane];
        bsA[q] = bih[q * 128 + lane] + bhh[q * 128 + lane];
        bsB[q] = bih[q * 128 + 64 + lane] + bhh[q * 128 + 64 + lane];
    }
    const float fcwa = fcW[lane];
    const float fcwb = fcW[64 + lane];
    const float fcw2 = fcW[128], fcb0 = fcb[0];
    __syncthreads();

    #pragma unroll 1
    for (int s = 0; s < TN; ++s) {
        const int m = lane & 15, q = lane >> 4;
        FU a4[4];                       // d-part A-frags, live through ph2 (gates)
        // ==== region A: p-MFMA only (2 accumulators to halve the serial chain) ====
        {
            #pragma unroll
            for (int kt = 0; kt < 4; ++kt) {
                int slot = ((kt * 4 + q) & 15) ^ m;      // d-part chunks
                a4[kt].u = *(const uint4*)&sm.dc[m * 256 + slot * 8];
            }
            float4v pacc1 = (float4v){0.f, 0.f, 0.f, 0.f};
            float4v pacc2 = (float4v){0.f, 0.f, 0.f, 0.f};
            #pragma unroll
            for (int kt = 0; kt < 4; ++kt) {
                FU b; b.u = w1f[kt];
                pacc1 = __builtin_amdgcn_mfma_f32_16x16x32_f16(a4[kt].h8, b.h8, pacc1, 0, 0, 0);
            }
            #pragma unroll
            for (int kt = 0; kt < 4; ++kt) {
                int slot = 16 | (((kt * 4 + q) & 15) ^ m);   // c-part chunks
                FU a; a.u = *(const uint4*)&sm.dc[m * 256 + slot * 8];
                FU b; b.u = w1f[4 + kt];
                pacc2 = __builtin_amdgcn_mfma_f32_16x16x32_f16(a.h8, b.h8, pacc2, 0, 0, 0);
            }
            if (lane < 32) {
                const int row0 = (lane >> 4) * 4, col = lane & 15;
                #pragma unroll
                for (int r = 0; r < 4; ++r)
                    sm.spH[(row0 + r) * 128 + wv * 16 + col] =
                        __float2half(pacc1[r] + pacc2[r]);
            }
        }
        __syncthreads();   // b1a: spH ready

        // ==== ph2: gates-MFMA issued under the e-loop (MFMA pipe || VALU/trans) ====
        float4v gacc[4];
        {
            #pragma unroll
            for (int i = 0; i < 4; ++i) gacc[i] = (float4v){0.f, 0.f, 0.f, 0.f};
            #pragma unroll
            for (int i = 0; i < 4; ++i) {
                #pragma unroll
                for (int kt = 0; kt < 4; ++kt) {
                    FU b; b.u = wtf[i * 4 + kt];
                    gacc[i] = __builtin_amdgcn_mfma_f32_16x16x32_f16(a4[kt].h8, b.h8, gacc[i], 0, 0, 0);
                }
            }
        }
        float ctxA, ctxB, ea;
        {
            // e-loop: ea[t=lane] = sum_f 2*w2[f]*sigma(2x) (inputs pre-scaled by KK)
            const uint4* pH = (const uint4*)&sm.spH[g * 128];
            const __half2* w2b = (const __half2*)sm.w2h;
            const __half2 one2 = __float2half2_rn(1.f);
            float ea0 = 0.f, ea1 = 0.f, ea2 = 0.f, ea3 = 0.f;
            #pragma unroll
            for (int u = 0; u < 16; ++u) {
                FU hw; hw.u = hwr[u];
                FU pp; pp.u = pH[u];
                __half2 th0 = sig2(__hadd2(hw.h2[0], pp.h2[0]), one2);
                __half2 th1 = sig2(__hadd2(hw.h2[1], pp.h2[1]), one2);
                __half2 th2 = sig2(__hadd2(hw.h2[2], pp.h2[2]), one2);
                __half2 th3 = sig2(__hadd2(hw.h2[3], pp.h2[3]), one2);
                ea0 = fdot2f(th0, w2b[u * 4 + 0], ea0);
                ea1 = fdot2f(th1, w2b[u * 4 + 1], ea1);
                ea2 = fdot2f(th2, w2b[u * 4 + 2], ea2);
                ea3 = fdot2f(th3, w2b[u * 4 + 3], ea3);
            }
            ea = (ea0 + ea1) + (ea2 + ea3);
            // gate MFMA results -> LDS (completed long ago; hides under e-loop)
            if (lane < 32) {
                const int row0 = (lane >> 4) * 4, col = lane & 15;
                #pragma unroll
                for (int i = 0; i < 4; ++i) {
                    #pragma unroll
                    for (int r = 0; r < 4; ++r)
                        sm.sg[(row0 + r) * 512 + (wv * 4 + i) * 16 + col] = gacc[i][r];
                }
            }
            // softmax over t (|ea| bounded ~35, fp32 safe, no max pass)
            float ex = __expf(ea);
            float ssum = wave_sum64(ex);
            sm.beta[g * 64 + lane] = __float2half(ex * __builtin_amdgcn_rcpf(ssum));
            // ctx for f=lane and f=lane+64 (same-wave LDS readback of beta)
            const uint4* bb = (const uint4*)&sm.beta[g * 64];
            const uint4* htb = (const uint4*)sm.ht;
            const int ba = ((g << 7) | lane) << 3;
            const int sw7 = lane & 7;
            float ca0 = 0.f, ca1 = 0.f, cb0 = 0.f, cb1 = 0.f;
            #pragma unroll
            for (int u = 0; u < 8; ++u) {
                FU bt; bt.u = bb[u];
                FU h0; h0.u = htb[ba + (u ^ sw7)];
                FU h1; h1.u = htb[ba + 512 + (u ^ sw7)];
                ca0 = fdot2f(h0.h2[0], bt.h2[0], ca0);
                ca1 = fdot2f(h0.h2[1], bt.h2[1], ca1);
                ca0 = fdot2f(h0.h2[2], bt.h2[2], ca0);
                ca1 = fdot2f(h0.h2[3], bt.h2[3], ca1);
                cb0 = fdot2f(h1.h2[0], bt.h2[0], cb0);
                cb1 = fdot2f(h1.h2[1], bt.h2[1], cb1);
                cb0 = fdot2f(h1.h2[2], bt.h2[2], cb0);
                cb1 = fdot2f(h1.h2[3], bt.h2[3], cb1);
            }
            ctxA = ca0 + ca1; ctxB = cb0 + cb1;
            if (s == TN - 1) {                         // epilogue-only data
                sm.ctxH[g * 128 + lane] = __float2half(ctxA);
                sm.ctxH[g * 128 + 64 + lane] = __float2half(ctxB);
            }
        }
        __syncthreads();   // b1b: sg ready

        // ==== ph3 tail: y~ + LSTM ====
        {
            float v = wave_sum64(ctxA * fcwa + ctxB * fcwb);
            float syg = v + fmaf(sm.sY[g * 64 + s], fcw2, fcb0);
            float a0A = sm.sg[g * 512 + lane]       + fmaf(syg, wihA[0], bsA[0]);
            float a1A = sm.sg[g * 512 + 128 + lane] + fmaf(syg, wihA[1], bsA[1]);
            float a2A = sm.sg[g * 512 + 256 + lane] + fmaf(syg, wihA[2], bsA[2]);
            float a3A = sm.sg[g * 512 + 384 + lane] + fmaf(syg, wihA[3], bsA[3]);
            float a0B = sm.sg[g * 512 + 64 + lane]  + fmaf(syg, wihB[0], bsB[0]);
            float a1B = sm.sg[g * 512 + 192 + lane] + fmaf(syg, wihB[1], bsB[1]);
            float a2B = sm.sg[g * 512 + 320 + lane] + fmaf(syg, wihB[2], bsB[2]);
            float a3B = sm.sg[g * 512 + 448 + lane] + fmaf(syg, wihB[3], bsB[3]);
            float iA = fast_sigmoid(a0A), fA = fast_sigmoid(a1A);
            float gA = fast_tanhf(a2A),  oA = fast_sigmoid(a3A);
            c0 = fmaf(fA, c0, iA * gA);
            float dA = oA * fast_tanhf(c0);
            float iB = fast_sigmoid(a0B), fB = fast_sigmoid(a1B);
            float gB = fast_tanhf(a2B),  oB = fast_sigmoid(a3B);
            c1 = fmaf(fB, c1, iB * gB);
            float dB = oB * fast_tanhf(c1);
            sm.dc[dc_off(g, lane)] = __float2half(dA);
            sm.dc[dc_off(g, 64 + lane)] = __float2half(dB);
            sm.dc[dc_off(g, 128 + lane)] = __float2half(c0);
            sm.dc[dc_off(g, 192 + lane)] = __float2half(c1);
        }
        __syncthreads();   // b2 (step end)
    }

    // ---- epilogue: all 8 waves, wave-local data ----
    {
        float part = __half2float(sm.dc[dc_off(g, lane)]) * fcfW[lane]
                   + __half2float(sm.dc[dc_off(g, 64 + lane)]) * fcfW[64 + lane]
                   + __half2float(sm.ctxH[g * 128 + lane]) * fcfW[128 + lane]
                   + __half2float(sm.ctxH[g * 128 + 64 + lane]) * fcfW[192 + lane];
        #pragma unroll
        for (int d = 1; d < 64; d <<= 1) part += __shfl_xor(part, d, 64);
        if (lane == 0) out[bbase + g] = part + fcfb[0];
    }
}

extern "C" void kernel_launch(void* const* d_in, const int* in_sizes, int n_in,
                              void* d_out, int out_size, void* d_ws, size_t ws_size,
                              hipStream_t stream) {
    const float* H    = (const float*)d_in[0];
    const float* Y    = (const float*)d_in[1];
    const float* W1   = (const float*)d_in[2];
    const float* b1   = (const float*)d_in[3];
    const float* W2   = (const float*)d_in[4];
    // d_in[5] = attn_b2: softmax-shift-invariant, unused
    const float* Wih  = (const float*)d_in[6];
    const float* Whh  = (const float*)d_in[7];
    const float* bih  = (const float*)d_in[8];
    const float* bhh  = (const float*)d_in[9];
    const float* fcW  = (const float*)d_in[10];
    const float* fcb  = (const float*)d_in[11];
    const float* fcfW = (const float*)d_in[12];
    const float* fcfb = (const float*)d_in[13];

    char* ws = (char*)d_ws;
    __half* HWh = (__half*)ws;                            // 32 MB
    __half* HhT = (__half*)(ws + 33554432);               // 32 MB
    __half* W1m = (__half*)(ws + 2 * 33554432);           // 64 KB
    __half* WTm = (__half*)(ws + 2 * 33554432 + 65536);   // 128 KB
    float* out = (float*)d_out;

    prep_hw<<<BN * TN / 16, 256, 0, stream>>>(H, W1, b1, HWh);
    prep_ht<<<BN, 256, 0, stream>>>(H, HhT);
    prep_w1m<<<128, 256, 0, stream>>>(W1, W1m);
    prep_wtm<<<256, 256, 0, stream>>>(Whh, WTm);
    decoder_scan<<<NBLK, 512, 0, stream>>>(Y, W2, Wih, bih, bhh,
                                           fcW, fcb, fcfW, fcfb,
                                           HWh, HhT, (const uint4*)W1m,
                                           (const uint4*)WTm, out);
}

// Round 6
// 577.791 us; speedup vs baseline: 2.4505x; 2.4505x over previous
//
#include <hip/hip_runtime.h>
#include <hip/hip_fp16.h>

#define TN 64
#define BN 2048
#define G 8
#define NBLK (BN / G)   // 256 blocks x 512 threads, 1 block/CU, SINGLE round

// KK = -2/ln2: pre-scales attention-tanh inputs so e-loop computes
// sigma(2x) = 1/(1 + 2^(KK*x)) with no per-element multiply.
#define KK (-2.88539008f)

typedef _Float16 h2v __attribute__((ext_vector_type(2)));
typedef _Float16 half8 __attribute__((ext_vector_type(8)));
typedef float float4v __attribute__((ext_vector_type(4)));

union FU {
    uint4 u;
    half8 h8;
    h2v hv[4];
    __half2 h2[4];
    _Float16 f16[8];
};
union H2U { __half2 h; h2v v; };

#define LAUNDER4(v) asm volatile("" : "+v"((v).x), "+v"((v).y), "+v"((v).z), "+v"((v).w))

__device__ __forceinline__ float fast_sigmoid(float x) {
    return __builtin_amdgcn_rcpf(1.f + __expf(-x));
}
__device__ __forceinline__ float fast_tanhf(float x) {
    return fmaf(2.f, fast_sigmoid(2.f * x), -1.f);
}
__device__ __forceinline__ float fdot2f(__half2 a, __half2 b, float c) {
    H2U ua; ua.h = a; H2U ub; ub.h = b;
    return __builtin_amdgcn_fdot2(ua.v, ub.v, c, false);
}
// packed fp16 sigmoid(2x) where xs = KK*x is PRE-SCALED (KK folded into HWh/W1m):
// tv = 2^xs = e^{-2x}; r = 1/(1+tv). tanh(x) = 2r-1 is folded into softmax
// shift-invariance (e-loop accumulates 2*w2*r via pre-doubled w2h).
__device__ __forceinline__ __half2 sig2(__half2 xs, __half2 one2) {
    __half2 tv = h2exp2(xs);
    return h2rcp(__hadd2(tv, one2));
}

// wave64 sum via DPP (row_shr 1/2/4/8 + row_bcast15/31), result broadcast from
// lane 63. ~80 cyc vs ~250+ for 6 dependent ds_bpermute shuffles.
__device__ __forceinline__ float wave_sum64(float x) {
    union FI { float f; int i; };
    FI a, b; a.f = x;
    b.i = __builtin_amdgcn_update_dpp(0, a.i, 0x111, 0xf, 0xf, true); a.f += b.f;
    b.i = __builtin_amdgcn_update_dpp(0, a.i, 0x112, 0xf, 0xf, true); a.f += b.f;
    b.i = __builtin_amdgcn_update_dpp(0, a.i, 0x114, 0xf, 0xf, true); a.f += b.f;
    b.i = __builtin_amdgcn_update_dpp(0, a.i, 0x118, 0xf, 0xf, true); a.f += b.f;
    b.i = __builtin_amdgcn_update_dpp(0, a.i, 0x142, 0xf, 0xf, true); a.f += b.f;
    b.i = __builtin_amdgcn_update_dpp(0, a.i, 0x143, 0xf, 0xf, true); a.f += b.f;
    FI r; r.i = __builtin_amdgcn_readlane(a.i, 63);
    return r.f;
}

// dc swizzled offset (halves): chunk c of row g at slot (c&16)|((c&15)^g)
__device__ __forceinline__ int dc_off(int g, int e) {
    int c = e >> 3;
    int slot = (c & 16) | ((c & 15) ^ (g & 15));
    return g * 256 + slot * 8 + (e & 7);
}

// ---- HW[b,t,f] = KK * (H[b,t,:] @ W1[256:384,:] + b1), fp16 linear [b*T+t][128]
__global__ __launch_bounds__(256) void prep_hw(
    const float* __restrict__ H, const float* __restrict__ W1,
    const float* __restrict__ b1, __half* __restrict__ HWh) {
    __shared__ float sH[16 * 128];
    const int i = threadIdx.x;
    const long r0 = (long)blockIdx.x * 16;
    #pragma unroll
    for (int u = 0; u < 8; ++u) sH[u * 256 + i] = H[r0 * 128 + u * 256 + i];
    __syncthreads();
    const int f = i & 127;
    const int half_ = i >> 7;
    float acc[8];
    float bb = b1[f];
    #pragma unroll
    for (int u = 0; u < 8; ++u) acc[u] = bb;
    #pragma unroll 4
    for (int h = 0; h < 128; ++h) {
        float wv = W1[(256 + h) * 128 + f];
        #pragma unroll
        for (int u = 0; u < 8; ++u)
            acc[u] = fmaf(sH[(half_ + 2 * u) * 128 + h], wv, acc[u]);
    }
    #pragma unroll
    for (int u = 0; u < 8; ++u)
        HWh[(r0 + half_ + 2 * u) * 128 + f] = __float2half(KK * acc[u]);
}

// ---- HhT[b][f][t] = fp16(H[b][t][f])
__global__ __launch_bounds__(256) void prep_ht(
    const float* __restrict__ H, __half* __restrict__ HhT) {
    __shared__ __half sh[64 * 128];
    const int b = blockIdx.x, i = threadIdx.x;
    #pragma unroll
    for (int u = 0; u < 32; ++u) {
        int idx = u * 256 + i;
        sh[idx] = __float2half(H[(long)b * 8192 + idx]);
    }
    __syncthreads();
    const int f = i >> 1, t0 = (i & 1) * 32;
    __half* ob = HhT + (long)b * 8192 + (long)i * 32;
    #pragma unroll
    for (int k = 0; k < 32; ++k) ob[k] = sh[(t0 + k) * 128 + f];
}

// ---- W1m: KK * W1[0:256][:] in MFMA B-frag layout (frag fi = w*8+kt)
__global__ __launch_bounds__(256) void prep_w1m(
    const float* __restrict__ W1, __half* __restrict__ W1m) {
    int tid = blockIdx.x * 256 + threadIdx.x;   // 32768
    int fi = tid >> 9, rem = tid & 511, l = rem >> 3, j = rem & 7;
    int w = fi >> 3, kt = fi & 7;
    int row = kt * 32 + (l >> 4) * 8 + j;
    int col = w * 16 + (l & 15);
    W1m[tid] = __float2half(KK * W1[row * 128 + col]);
}

// ---- WTm: Whh^T in MFMA B-frag layout (frag fi = nt*4+kt)
__global__ __launch_bounds__(256) void prep_wtm(
    const float* __restrict__ Whh, __half* __restrict__ WTm) {
    int tid = blockIdx.x * 256 + threadIdx.x;   // 65536
    int fi = tid >> 9, rem = tid & 511, l = rem >> 3, j = rem & 7;
    int nt = fi >> 2, kt = fi & 3;
    int k = kt * 32 + (l >> 4) * 8 + j;
    int n = nt * 16 + (l & 15);
    WTm[tid] = __float2half(Whh[n * 128 + k]);
}

struct SMem {
    __half ht[G * 128 * 64];   // 131072 B  H^T tile [g][f][t], granule-XOR swizzle
    __half dc[G * 256];        //   4096 B  dc_off swizzle
    float sg[G * 512];         //  16384 B  gates [g][512]
    __half spH[G * 128];       //   2048 B  p fp16 [g][128] (KK-scaled)
    __half ctxH[G * 128];      //   2048 B  ctx fp16 [g][128] (written final step only)
    __half beta[G * 64];       //   1024 B  fp16 beta [g][64]
    __half w2h[128];           //    256 B  (pre-doubled: 2*W2, folds softmax 2x)
    float sY[G * 64];          //   2048 B
};                             // 158976 B total, 1 block/CU

__global__ __launch_bounds__(512, 2) void decoder_scan(
    const float* __restrict__ Y, const float* __restrict__ W2,
    const float* __restrict__ Wih, const float* __restrict__ bih,
    const float* __restrict__ bhh, const float* __restrict__ fcW,
    const float* __restrict__ fcb, const float* __restrict__ fcfW,
    const float* __restrict__ fcfb,
    const __half* __restrict__ HWh, const __half* __restrict__ HhT,
    const uint4* __restrict__ W1m4, const uint4* __restrict__ WTm4,
    float* __restrict__ out) {

    __shared__ SMem sm;

    const int tid = threadIdx.x;
    const int bbase = blockIdx.x * G;
    const int lane = tid & 63;
    const int wv = tid >> 6;            // wave id == batch-group g
    const int g = wv;

    // ---- init ----
    // HW[g][t=lane][0..127] -> laundered registers (64 VGPR)
    uint4 hwr[16];
    {
        const uint4* src = (const uint4*)(HWh + (((long)(bbase + g) * TN + lane) * 128));
        #pragma unroll
        for (int u = 0; u < 16; ++u) { hwr[u] = src[u]; LAUNDER4(hwr[u]); }
    }
    // H^T tile -> LDS with granule swizzle (granule u of row at u ^ (f&7))
    {
        const uint4* src = (const uint4*)(HhT + (long)bbase * 8192);
        #pragma unroll
        for (int u = 0; u < 16; ++u) {
            int idx = u * 512 + tid;             // granule 0..8191
            int f7 = (idx >> 3) & 7;
            ((uint4*)sm.ht)[(idx & ~7) | ((idx & 7) ^ f7)] = src[idx];
        }
    }
    // W1 B-frags (8 = 32 regs), WhhT B-frags (16 = 64 regs), laundered (AGPR-ok)
    uint4 w1f[8];
    #pragma unroll
    for (int kt = 0; kt < 8; ++kt) {
        w1f[kt] = W1m4[(size_t)(wv * 8 + kt) * 64 + lane];
        LAUNDER4(w1f[kt]);
    }
    uint4 wtf[16];
    #pragma unroll
    for (int q = 0; q < 16; ++q) {
        wtf[q] = WTm4[(size_t)(wv * 16 + q) * 64 + lane];
        LAUNDER4(wtf[q]);
    }
    ((unsigned*)sm.dc)[tid] = 0u;
    ((unsigned*)sm.dc)[512 + tid] = 0u;
    if (tid < 128) sm.w2h[tid] = __float2half(2.f * W2[tid]);   // fold softmax 2x
    sm.sY[tid] = Y[(long)bbase * TN + tid];
    float c0 = 0.f, c1 = 0.f;
    float wihA[4], wihB[4], bsA[4], bsB[4];
    #pragma unroll
    for (int q = 0; q < 4; ++q) {
        wihA[q] = Wih[q * 128 + lane];
        wihB[q] = Wih[q * 128 + 64 + lane];
        bsA[q] = bih[q * 128 + lane] + bhh[q * 128 + lane];
        bsB[q] = bih[q * 128 + 64 + lane] + bhh[q * 128 + 64 + lane];
    }
    const float fcwa = fcW[lane];
    const float fcwb = fcW[64 + lane];
    const float fcw2 = fcW[128], fcb0 = fcb[0];
    __syncthreads();

    #pragma unroll 1
    for (int s = 0; s < TN; ++s) {
        // ==== region A: p + gates MFMAs (rows = g, 8/16 real) ====
        // All fragment registers (a4, pacc, gacc) die before b1 -- no lifetime
        // extension across barriers (R5 lesson: +32 live regs in ph2 => spill).
        {
            const int m = lane & 15, q = lane >> 4;
            FU a4[4];
            #pragma unroll
            for (int kt = 0; kt < 4; ++kt) {
                int slot = ((kt * 4 + q) & 15) ^ m;      // d-part chunks
                a4[kt].u = *(const uint4*)&sm.dc[m * 256 + slot * 8];
            }
            // p: two accumulators halve the serial MFMA dependency chain
            float4v pacc1 = (float4v){0.f, 0.f, 0.f, 0.f};
            float4v pacc2 = (float4v){0.f, 0.f, 0.f, 0.f};
            float4v gacc[4];
            #pragma unroll
            for (int i = 0; i < 4; ++i) gacc[i] = (float4v){0.f, 0.f, 0.f, 0.f};
            #pragma unroll
            for (int kt = 0; kt < 4; ++kt) {
                FU b; b.u = w1f[kt];
                pacc1 = __builtin_amdgcn_mfma_f32_16x16x32_f16(a4[kt].h8, b.h8, pacc1, 0, 0, 0);
            }
            #pragma unroll
            for (int i = 0; i < 4; ++i) {
                #pragma unroll
                for (int kt = 0; kt < 4; ++kt) {
                    FU b; b.u = wtf[i * 4 + kt];
                    gacc[i] = __builtin_amdgcn_mfma_f32_16x16x32_f16(a4[kt].h8, b.h8, gacc[i], 0, 0, 0);
                }
            }
            #pragma unroll
            for (int kt = 0; kt < 4; ++kt) {
                int slot = 16 | (((kt * 4 + q) & 15) ^ m);   // c-part chunks
                FU a; a.u = *(const uint4*)&sm.dc[m * 256 + slot * 8];
                FU b; b.u = w1f[4 + kt];
                pacc2 = __builtin_amdgcn_mfma_f32_16x16x32_f16(a.h8, b.h8, pacc2, 0, 0, 0);
            }
            if (lane < 32) {
                const int row0 = (lane >> 4) * 4, col = lane & 15;
                #pragma unroll
                for (int r = 0; r < 4; ++r)
                    sm.spH[(row0 + r) * 128 + wv * 16 + col] =
                        __float2half(pacc1[r] + pacc2[r]);
                #pragma unroll
                for (int i = 0; i < 4; ++i) {
                    #pragma unroll
                    for (int r = 0; r < 4; ++r)
                        sm.sg[(row0 + r) * 512 + (wv * 4 + i) * 16 + col] = gacc[i][r];
                }
            }
        }
        __syncthreads();   // b1

        // ==== phase 3: wave-local for own g: e -> softmax -> ctx -> y~ -> LSTM ====
        {
            // ph2: ea[t=lane] = sum_f 2*w2[f]*sigma(2x) (inputs pre-scaled by KK;
            // w2h pre-doubled so softmax arg is ea directly).
            const uint4* pH = (const uint4*)&sm.spH[g * 128];
            const __half2* w2b = (const __half2*)sm.w2h;
            const __half2 one2 = __float2half2_rn(1.f);
            float ea0 = 0.f, ea1 = 0.f, ea2 = 0.f, ea3 = 0.f;
            #pragma unroll
            for (int u = 0; u < 16; ++u) {
                FU hw; hw.u = hwr[u];
                FU pp; pp.u = pH[u];
                __half2 th0 = sig2(__hadd2(hw.h2[0], pp.h2[0]), one2);
                __half2 th1 = sig2(__hadd2(hw.h2[1], pp.h2[1]), one2);
                __half2 th2 = sig2(__hadd2(hw.h2[2], pp.h2[2]), one2);
                __half2 th3 = sig2(__hadd2(hw.h2[3], pp.h2[3]), one2);
                ea0 = fdot2f(th0, w2b[u * 4 + 0], ea0);
                ea1 = fdot2f(th1, w2b[u * 4 + 1], ea1);
                ea2 = fdot2f(th2, w2b[u * 4 + 2], ea2);
                ea3 = fdot2f(th3, w2b[u * 4 + 3], ea3);
            }
            float ea = (ea0 + ea1) + (ea2 + ea3);
            // softmax over t (|ea| bounded ~35, fp32 safe, no max pass)
            float ex = __expf(ea);
            float ssum = wave_sum64(ex);
            sm.beta[g * 64 + lane] = __float2half(ex * __builtin_amdgcn_rcpf(ssum));
            // ctx for f=lane and f=lane+64 (same-wave LDS readback of beta)
            const uint4* bb = (const uint4*)&sm.beta[g * 64];
            const uint4* htb = (const uint4*)sm.ht;
            const int ba = ((g << 7) | lane) << 3;
            const int sw7 = lane & 7;
            float ca0 = 0.f, ca1 = 0.f, cb0 = 0.f, cb1 = 0.f;
            #pragma unroll
            for (int u = 0; u < 8; ++u) {
                FU bt; bt.u = bb[u];
                FU h0; h0.u = htb[ba + (u ^ sw7)];
                FU h1; h1.u = htb[ba + 512 + (u ^ sw7)];
                ca0 = fdot2f(h0.h2[0], bt.h2[0], ca0);
                ca1 = fdot2f(h0.h2[1], bt.h2[1], ca1);
                ca0 = fdot2f(h0.h2[2], bt.h2[2], ca0);
                ca1 = fdot2f(h0.h2[3], bt.h2[3], ca1);
                cb0 = fdot2f(h1.h2[0], bt.h2[0], cb0);
                cb1 = fdot2f(h1.h2[1], bt.h2[1], cb1);
                cb0 = fdot2f(h1.h2[2], bt.h2[2], cb0);
                cb1 = fdot2f(h1.h2[3], bt.h2[3], cb1);
            }
            float ctxA = ca0 + ca1, ctxB = cb0 + cb1;
            if (s == TN - 1) {                         // epilogue-only data
                sm.ctxH[g * 128 + lane] = __float2half(ctxA);
                sm.ctxH[g * 128 + 64 + lane] = __float2half(ctxB);
            }
            // y~ via DPP wave reduce (covers all 128 f: own + mirror)
            float v = wave_sum64(ctxA * fcwa + ctxB * fcwb);
            float syg = v + fmaf(sm.sY[g * 64 + s], fcw2, fcb0);
            // LSTM cell for feats lane and lane+64
            float a0A = sm.sg[g * 512 + lane]       + fmaf(syg, wihA[0], bsA[0]);
            float a1A = sm.sg[g * 512 + 128 + lane] + fmaf(syg, wihA[1], bsA[1]);
            float a2A = sm.sg[g * 512 + 256 + lane] + fmaf(syg, wihA[2], bsA[2]);
            float a3A = sm.sg[g * 512 + 384 + lane] + fmaf(syg, wihA[3], bsA[3]);
            float a0B = sm.sg[g * 512 + 64 + lane]  + fmaf(syg, wihB[0], bsB[0]);
            float a1B = sm.sg[g * 512 + 192 + lane] + fmaf(syg, wihB[1], bsB[1]);
            float a2B = sm.sg[g * 512 + 320 + lane] + fmaf(syg, wihB[2], bsB[2]);
            float a3B = sm.sg[g * 512 + 448 + lane] + fmaf(syg, wihB[3], bsB[3]);
            float iA = fast_sigmoid(a0A), fA = fast_sigmoid(a1A);
            float gA = fast_tanhf(a2A),  oA = fast_sigmoid(a3A);
            c0 = fmaf(fA, c0, iA * gA);
            float dA = oA * fast_tanhf(c0);
            float iB = fast_sigmoid(a0B), fB = fast_sigmoid(a1B);
            float gB = fast_tanhf(a2B),  oB = fast_sigmoid(a3B);
            c1 = fmaf(fB, c1, iB * gB);
            float dB = oB * fast_tanhf(c1);
            sm.dc[dc_off(g, lane)] = __float2half(dA);
            sm.dc[dc_off(g, 64 + lane)] = __float2half(dB);
            sm.dc[dc_off(g, 128 + lane)] = __float2half(c0);
            sm.dc[dc_off(g, 192 + lane)] = __float2half(c1);
        }
        __syncthreads();   // b2 (step end)
    }

    // ---- epilogue: all 8 waves, wave-local data ----
    {
        float part = __half2float(sm.dc[dc_off(g, lane)]) * fcfW[lane]
                   + __half2float(sm.dc[dc_off(g, 64 + lane)]) * fcfW[64 + lane]
                   + __half2float(sm.ctxH[g * 128 + lane]) * fcfW[128 + lane]
                   + __half2float(sm.ctxH[g * 128 + 64 + lane]) * fcfW[192 + lane];
        #pragma unroll
        for (int d = 1; d < 64; d <<= 1) part += __shfl_xor(part, d, 64);
        if (lane == 0) out[bbase + g] = part + fcfb[0];
    }
}

extern "C" void kernel_launch(void* const* d_in, const int* in_sizes, int n_in,
                              void* d_out, int out_size, void* d_ws, size_t ws_size,
                              hipStream_t stream) {
    const float* H    = (const float*)d_in[0];
    const float* Y    = (const float*)d_in[1];
    const float* W1   = (const float*)d_in[2];
    const float* b1   = (const float*)d_in[3];
    const float* W2   = (const float*)d_in[4];
    // d_in[5] = attn_b2: softmax-shift-invariant, unused
    const float* Wih  = (const float*)d_in[6];
    const float* Whh  = (const float*)d_in[7];
    const float* bih  = (const float*)d_in[8];
    const float* bhh  = (const float*)d_in[9];
    const float* fcW  = (const float*)d_in[10];
    const float* fcb  = (const float*)d_in[11];
    const float* fcfW = (const float*)d_in[12];
    const float* fcfb = (const float*)d_in[13];

    char* ws = (char*)d_ws;
    __half* HWh = (__half*)ws;                            // 32 MB
    __half* HhT = (__half*)(ws + 33554432);               // 32 MB
    __half* W1m = (__half*)(ws + 2 * 33554432);           // 64 KB
    __half* WTm = (__half*)(ws + 2 * 33554432 + 65536);   // 128 KB
    float* out = (float*)d_out;

    prep_hw<<<BN * TN / 16, 256, 0, stream>>>(H, W1, b1, HWh);
    prep_ht<<<BN, 256, 0, stream>>>(H, HhT);
    prep_w1m<<<128, 256, 0, stream>>>(W1, W1m);
    prep_wtm<<<256, 256, 0, stream>>>(Whh, WTm);
    decoder_scan<<<NBLK, 512, 0, stream>>>(Y, W2, Wih, bih, bhh,
                                           fcW, fcb, fcfW, fcfb,
                                           HWh, HhT, (const uint4*)W1m,
                                           (const uint4*)WTm, out);
}

// Round 7
// 492.655 us; speedup vs baseline: 2.8740x; 1.1728x over previous
//
#include <hip/hip_runtime.h>
#include <hip/hip_fp16.h>

#define TN 64
#define BN 2048
#define G 8
#define NBLK (BN / G)   // 256 blocks x 512 threads, 1 block/CU, SINGLE round

// KK = -2/ln2. Attention tanh is computed as sigma(2x) = 1/(1 + 2^(KK*x)),
// with the exponential FACTORED: 2^(KK*(hw+p)) = E*P where E = 2^(KK*hw)
// (precomputed in prep_hw, step-invariant) and P = 2^(KK*p) (computed once
// per step per f in region A, t-invariant). The e-loop then needs NO exp —
// just hfma2 + h2rcp per pair. Exponents clamped to +-14 (fp16-safe;
// distortion only where sigma < 2^-13, error < 1e-4).
#define KK (-2.88539008f)

typedef _Float16 h2v __attribute__((ext_vector_type(2)));
typedef _Float16 half8 __attribute__((ext_vector_type(8)));
typedef float float4v __attribute__((ext_vector_type(4)));

union FU {
    uint4 u;
    half8 h8;
    h2v hv[4];
    __half2 h2[4];
    _Float16 f16[8];
};
union H2U { __half2 h; h2v v; };

#define LAUNDER4(v) asm volatile("" : "+v"((v).x), "+v"((v).y), "+v"((v).z), "+v"((v).w))

__device__ __forceinline__ float fast_sigmoid(float x) {
    return __builtin_amdgcn_rcpf(1.f + __expf(-x));
}
__device__ __forceinline__ float fast_tanhf(float x) {
    return fmaf(2.f, fast_sigmoid(2.f * x), -1.f);
}
__device__ __forceinline__ float fdot2f(__half2 a, __half2 b, float c) {
    H2U ua; ua.h = a; H2U ub; ub.h = b;
    return __builtin_amdgcn_fdot2(ua.v, ub.v, c, false);
}

// wave64 sum via DPP (row_shr 1/2/4/8 + row_bcast15/31), result broadcast from
// lane 63. ~80 cyc vs ~250+ for 6 dependent ds_bpermute shuffles.
__device__ __forceinline__ float wave_sum64(float x) {
    union FI { float f; int i; };
    FI a, b; a.f = x;
    b.i = __builtin_amdgcn_update_dpp(0, a.i, 0x111, 0xf, 0xf, true); a.f += b.f;
    b.i = __builtin_amdgcn_update_dpp(0, a.i, 0x112, 0xf, 0xf, true); a.f += b.f;
    b.i = __builtin_amdgcn_update_dpp(0, a.i, 0x114, 0xf, 0xf, true); a.f += b.f;
    b.i = __builtin_amdgcn_update_dpp(0, a.i, 0x118, 0xf, 0xf, true); a.f += b.f;
    b.i = __builtin_amdgcn_update_dpp(0, a.i, 0x142, 0xf, 0xf, true); a.f += b.f;
    b.i = __builtin_amdgcn_update_dpp(0, a.i, 0x143, 0xf, 0xf, true); a.f += b.f;
    FI r; r.i = __builtin_amdgcn_readlane(a.i, 63);
    return r.f;
}

// dc swizzled offset (halves): chunk c of row g at slot (c&16)|((c&15)^g)
__device__ __forceinline__ int dc_off(int g, int e) {
    int c = e >> 3;
    int slot = (c & 16) | ((c & 15) ^ (g & 15));
    return g * 256 + slot * 8 + (e & 7);
}

// ---- HW[b,t,f] = E = 2^(KK*(H[b,t,:] @ W1[256:384,:] + b1)), fp16 [b*T+t][128]
__global__ __launch_bounds__(256) void prep_hw(
    const float* __restrict__ H, const float* __restrict__ W1,
    const float* __restrict__ b1, __half* __restrict__ HWh) {
    __shared__ float sH[16 * 128];
    const int i = threadIdx.x;
    const long r0 = (long)blockIdx.x * 16;
    #pragma unroll
    for (int u = 0; u < 8; ++u) sH[u * 256 + i] = H[r0 * 128 + u * 256 + i];
    __syncthreads();
    const int f = i & 127;
    const int half_ = i >> 7;
    float acc[8];
    float bb = b1[f];
    #pragma unroll
    for (int u = 0; u < 8; ++u) acc[u] = bb;
    #pragma unroll 4
    for (int h = 0; h < 128; ++h) {
        float wv = W1[(256 + h) * 128 + f];
        #pragma unroll
        for (int u = 0; u < 8; ++u)
            acc[u] = fmaf(sH[(half_ + 2 * u) * 128 + h], wv, acc[u]);
    }
    #pragma unroll
    for (int u = 0; u < 8; ++u) {
        float z = fminf(fmaxf(KK * acc[u], -14.f), 14.f);
        HWh[(r0 + half_ + 2 * u) * 128 + f] = __float2half(exp2f(z));
    }
}

// ---- HhT[b][f][t] = fp16(H[b][t][f])
__global__ __launch_bounds__(256) void prep_ht(
    const float* __restrict__ H, __half* __restrict__ HhT) {
    __shared__ __half sh[64 * 128];
    const int b = blockIdx.x, i = threadIdx.x;
    #pragma unroll
    for (int u = 0; u < 32; ++u) {
        int idx = u * 256 + i;
        sh[idx] = __float2half(H[(long)b * 8192 + idx]);
    }
    __syncthreads();
    const int f = i >> 1, t0 = (i & 1) * 32;
    __half* ob = HhT + (long)b * 8192 + (long)i * 32;
    #pragma unroll
    for (int k = 0; k < 32; ++k) ob[k] = sh[(t0 + k) * 128 + f];
}

// ---- W1m: KK * W1[0:256][:] in MFMA B-frag layout (frag fi = w*8+kt)
__global__ __launch_bounds__(256) void prep_w1m(
    const float* __restrict__ W1, __half* __restrict__ W1m) {
    int tid = blockIdx.x * 256 + threadIdx.x;   // 32768
    int fi = tid >> 9, rem = tid & 511, l = rem >> 3, j = rem & 7;
    int w = fi >> 3, kt = fi & 7;
    int row = kt * 32 + (l >> 4) * 8 + j;
    int col = w * 16 + (l & 15);
    W1m[tid] = __float2half(KK * W1[row * 128 + col]);
}

// ---- WTm: Whh^T in MFMA B-frag layout (frag fi = nt*4+kt)
__global__ __launch_bounds__(256) void prep_wtm(
    const float* __restrict__ Whh, __half* __restrict__ WTm) {
    int tid = blockIdx.x * 256 + threadIdx.x;   // 65536
    int fi = tid >> 9, rem = tid & 511, l = rem >> 3, j = rem & 7;
    int nt = fi >> 2, kt = fi & 3;
    int k = kt * 32 + (l >> 4) * 8 + j;
    int n = nt * 16 + (l & 15);
    WTm[tid] = __float2half(Whh[n * 128 + k]);
}

struct SMem {
    __half ht[G * 128 * 64];   // 131072 B  H^T tile [g][f][t], granule-XOR swizzle
    __half dc[G * 256];        //   4096 B  dc_off swizzle
    float sg[G * 512];         //  16384 B  gates [g][512]
    __half spH[G * 128];       //   2048 B  P = 2^(KK*p) fp16 [g][128]
    __half ctxH[G * 128];      //   2048 B  ctx fp16 [g][128] (written final step only)
    __half beta[G * 64];       //   1024 B  fp16 beta [g][64]
    __half w2h[128];           //    256 B  (pre-scaled: 2*log2e*W2 = -KK*W2)
    float sY[G * 64];          //   2048 B
};                             // 158976 B total, 1 block/CU

__global__ __launch_bounds__(512, 2) void decoder_scan(
    const float* __restrict__ Y, const float* __restrict__ W2,
    const float* __restrict__ Wih, const float* __restrict__ bih,
    const float* __restrict__ bhh, const float* __restrict__ fcW,
    const float* __restrict__ fcb, const float* __restrict__ fcfW,
    const float* __restrict__ fcfb,
    const __half* __restrict__ HWh, const __half* __restrict__ HhT,
    const uint4* __restrict__ W1m4, const uint4* __restrict__ WTm4,
    float* __restrict__ out) {

    __shared__ SMem sm;

    const int tid = threadIdx.x;
    const int bbase = blockIdx.x * G;
    const int lane = tid & 63;
    const int wv = tid >> 6;            // wave id == batch-group g
    const int g = wv;

    // ---- init ----
    // E[g][t=lane][0..127] -> laundered registers (64 VGPR)
    uint4 hwr[16];
    {
        const uint4* src = (const uint4*)(HWh + (((long)(bbase + g) * TN + lane) * 128));
        #pragma unroll
        for (int u = 0; u < 16; ++u) { hwr[u] = src[u]; LAUNDER4(hwr[u]); }
    }
    // H^T tile -> LDS with granule swizzle (granule u of row at u ^ (f&7))
    {
        const uint4* src = (const uint4*)(HhT + (long)bbase * 8192);
        #pragma unroll
        for (int u = 0; u < 16; ++u) {
            int idx = u * 512 + tid;             // granule 0..8191
            int f7 = (idx >> 3) & 7;
            ((uint4*)sm.ht)[(idx & ~7) | ((idx & 7) ^ f7)] = src[idx];
        }
    }
    // W1 B-frags (8 = 32 regs), WhhT B-frags (16 = 64 regs), laundered (AGPR-ok)
    uint4 w1f[8];
    #pragma unroll
    for (int kt = 0; kt < 8; ++kt) {
        w1f[kt] = W1m4[(size_t)(wv * 8 + kt) * 64 + lane];
        LAUNDER4(w1f[kt]);
    }
    uint4 wtf[16];
    #pragma unroll
    for (int q = 0; q < 16; ++q) {
        wtf[q] = WTm4[(size_t)(wv * 16 + q) * 64 + lane];
        LAUNDER4(wtf[q]);
    }
    ((unsigned*)sm.dc)[tid] = 0u;
    ((unsigned*)sm.dc)[512 + tid] = 0u;
    if (tid < 128) sm.w2h[tid] = __float2half(-KK * W2[tid]);  // 2*log2e*W2
    sm.sY[tid] = Y[(long)bbase * TN + tid];
    float c0 = 0.f, c1 = 0.f;
    float wihA[4], wihB[4], bsA[4], bsB[4];
    #pragma unroll
    for (int q = 0; q < 4; ++q) {
        wihA[q] = Wih[q * 128 + lane];
        wihB[q] = Wih[q * 128 + 64 + lane];
        bsA[q] = bih[q * 128 + lane] + bhh[q * 128 + lane];
        bsB[q] = bih[q * 128 + 64 + lane] + bhh[q * 128 + 64 + lane];
    }
    const float fcwa = fcW[lane];
    const float fcwb = fcW[64 + lane];
    const float fcw2 = fcW[128], fcb0 = fcb[0];
    __syncthreads();

    #pragma unroll 1
    for (int s = 0; s < TN; ++s) {
        // ==== region A: p + gates MFMAs (rows = g, 8/16 real) ====
        // All fragment registers (a4, pacc, gacc) die before b1 -- no lifetime
        // extension across barriers (R5 lesson: +32 live regs in ph2 => spill).
        {
            const int m = lane & 15, q = lane >> 4;
            FU a4[4];
            #pragma unroll
            for (int kt = 0; kt < 4; ++kt) {
                int slot = ((kt * 4 + q) & 15) ^ m;      // d-part chunks
                a4[kt].u = *(const uint4*)&sm.dc[m * 256 + slot * 8];
            }
            // p: two accumulators halve the serial MFMA dependency chain
            float4v pacc1 = (float4v){0.f, 0.f, 0.f, 0.f};
            float4v pacc2 = (float4v){0.f, 0.f, 0.f, 0.f};
            float4v gacc[4];
            #pragma unroll
            for (int i = 0; i < 4; ++i) gacc[i] = (float4v){0.f, 0.f, 0.f, 0.f};
            #pragma unroll
            for (int kt = 0; kt < 4; ++kt) {
                FU b; b.u = w1f[kt];
                pacc1 = __builtin_amdgcn_mfma_f32_16x16x32_f16(a4[kt].h8, b.h8, pacc1, 0, 0, 0);
            }
            #pragma unroll
            for (int i = 0; i < 4; ++i) {
                #pragma unroll
                for (int kt = 0; kt < 4; ++kt) {
                    FU b; b.u = wtf[i * 4 + kt];
                    gacc[i] = __builtin_amdgcn_mfma_f32_16x16x32_f16(a4[kt].h8, b.h8, gacc[i], 0, 0, 0);
                }
            }
            #pragma unroll
            for (int kt = 0; kt < 4; ++kt) {
                int slot = 16 | (((kt * 4 + q) & 15) ^ m);   // c-part chunks
                FU a; a.u = *(const uint4*)&sm.dc[m * 256 + slot * 8];
                FU b; b.u = w1f[4 + kt];
                pacc2 = __builtin_amdgcn_mfma_f32_16x16x32_f16(a.h8, b.h8, pacc2, 0, 0, 0);
            }
            if (lane < 32) {
                const int row0 = (lane >> 4) * 4, col = lane & 15;
                #pragma unroll
                for (int r = 0; r < 4; ++r) {
                    // P = 2^(KK*p), clamped exponent (pacc is already KK-scaled)
                    float pv = fminf(fmaxf(pacc1[r] + pacc2[r], -14.f), 14.f);
                    sm.spH[(row0 + r) * 128 + wv * 16 + col] = __float2half(exp2f(pv));
                }
                #pragma unroll
                for (int i = 0; i < 4; ++i) {
                    #pragma unroll
                    for (int r = 0; r < 4; ++r)
                        sm.sg[(row0 + r) * 512 + (wv * 4 + i) * 16 + col] = gacc[i][r];
                }
            }
        }
        __syncthreads();   // b1

        // ==== phase 3: wave-local for own g: e -> softmax -> ctx -> y~ -> LSTM ====
        {
            // e-loop: sigma = rcp(1 + E*P) -- NO exp (factored into E, P).
            // ea[t=lane] = sum_f (-KK)*w2[f]*sigma; softmax arg = ea via exp2.
            const uint4* pH = (const uint4*)&sm.spH[g * 128];
            const __half2* w2b = (const __half2*)sm.w2h;
            const __half2 one2 = __float2half2_rn(1.f);
            float ea0 = 0.f, ea1 = 0.f, ea2 = 0.f, ea3 = 0.f;
            #pragma unroll
            for (int u = 0; u < 16; ++u) {
                FU hw; hw.u = hwr[u];
                FU pp; pp.u = pH[u];
                __half2 th0 = h2rcp(__hfma2(hw.h2[0], pp.h2[0], one2));
                __half2 th1 = h2rcp(__hfma2(hw.h2[1], pp.h2[1], one2));
                __half2 th2 = h2rcp(__hfma2(hw.h2[2], pp.h2[2], one2));
                __half2 th3 = h2rcp(__hfma2(hw.h2[3], pp.h2[3], one2));
                ea0 = fdot2f(th0, w2b[u * 4 + 0], ea0);
                ea1 = fdot2f(th1, w2b[u * 4 + 1], ea1);
                ea2 = fdot2f(th2, w2b[u * 4 + 2], ea2);
                ea3 = fdot2f(th3, w2b[u * 4 + 3], ea3);
            }
            float ea = (ea0 + ea1) + (ea2 + ea3);
            // softmax over t (base-2, w2h pre-scaled by log2e: exact same beta)
            float ex = exp2f(ea);
            float ssum = wave_sum64(ex);
            sm.beta[g * 64 + lane] = __float2half(ex * __builtin_amdgcn_rcpf(ssum));
            // ctx for f=lane and f=lane+64 (same-wave LDS readback of beta)
            const uint4* bb = (const uint4*)&sm.beta[g * 64];
            const uint4* htb = (const uint4*)sm.ht;
            const int ba = ((g << 7) | lane) << 3;
            const int sw7 = lane & 7;
            float ca0 = 0.f, ca1 = 0.f, cb0 = 0.f, cb1 = 0.f;
            #pragma unroll
            for (int u = 0; u < 8; ++u) {
                FU bt; bt.u = bb[u];
                FU h0; h0.u = htb[ba + (u ^ sw7)];
                FU h1; h1.u = htb[ba + 512 + (u ^ sw7)];
                ca0 = fdot2f(h0.h2[0], bt.h2[0], ca0);
                ca1 = fdot2f(h0.h2[1], bt.h2[1], ca1);
                ca0 = fdot2f(h0.h2[2], bt.h2[2], ca0);
                ca1 = fdot2f(h0.h2[3], bt.h2[3], ca1);
                cb0 = fdot2f(h1.h2[0], bt.h2[0], cb0);
                cb1 = fdot2f(h1.h2[1], bt.h2[1], cb1);
                cb0 = fdot2f(h1.h2[2], bt.h2[2], cb0);
                cb1 = fdot2f(h1.h2[3], bt.h2[3], cb1);
            }
            float ctxA = ca0 + ca1, ctxB = cb0 + cb1;
            if (s == TN - 1) {                         // epilogue-only data
                sm.ctxH[g * 128 + lane] = __float2half(ctxA);
                sm.ctxH[g * 128 + 64 + lane] = __float2half(ctxB);
            }
            // y~ via DPP wave reduce (covers all 128 f: own + mirror)
            float v = wave_sum64(ctxA * fcwa + ctxB * fcwb);
            float syg = v + fmaf(sm.sY[g * 64 + s], fcw2, fcb0);
            // LSTM cell for feats lane and lane+64
            float a0A = sm.sg[g * 512 + lane]       + fmaf(syg, wihA[0], bsA[0]);
            float a1A = sm.sg[g * 512 + 128 + lane] + fmaf(syg, wihA[1], bsA[1]);
            float a2A = sm.sg[g * 512 + 256 + lane] + fmaf(syg, wihA[2], bsA[2]);
            float a3A = sm.sg[g * 512 + 384 + lane] + fmaf(syg, wihA[3], bsA[3]);
            float a0B = sm.sg[g * 512 + 64 + lane]  + fmaf(syg, wihB[0], bsB[0]);
            float a1B = sm.sg[g * 512 + 192 + lane] + fmaf(syg, wihB[1], bsB[1]);
            float a2B = sm.sg[g * 512 + 320 + lane] + fmaf(syg, wihB[2], bsB[2]);
            float a3B = sm.sg[g * 512 + 448 + lane] + fmaf(syg, wihB[3], bsB[3]);
            float iA = fast_sigmoid(a0A), fA = fast_sigmoid(a1A);
            float gA = fast_tanhf(a2A),  oA = fast_sigmoid(a3A);
            c0 = fmaf(fA, c0, iA * gA);
            float dA = oA * fast_tanhf(c0);
            float iB = fast_sigmoid(a0B), fB = fast_sigmoid(a1B);
            float gB = fast_tanhf(a2B),  oB = fast_sigmoid(a3B);
            c1 = fmaf(fB, c1, iB * gB);
            float dB = oB * fast_tanhf(c1);
            sm.dc[dc_off(g, lane)] = __float2half(dA);
            sm.dc[dc_off(g, 64 + lane)] = __float2half(dB);
            sm.dc[dc_off(g, 128 + lane)] = __float2half(c0);
            sm.dc[dc_off(g, 192 + lane)] = __float2half(c1);
        }
        __syncthreads();   // b2 (step end)
    }

    // ---- epilogue: all 8 waves, wave-local data ----
    {
        float part = __half2float(sm.dc[dc_off(g, lane)]) * fcfW[lane]
                   + __half2float(sm.dc[dc_off(g, 64 + lane)]) * fcfW[64 + lane]
                   + __half2float(sm.ctxH[g * 128 + lane]) * fcfW[128 + lane]
                   + __half2float(sm.ctxH[g * 128 + 64 + lane]) * fcfW[192 + lane];
        #pragma unroll
        for (int d = 1; d < 64; d <<= 1) part += __shfl_xor(part, d, 64);
        if (lane == 0) out[bbase + g] = part + fcfb[0];
    }
}

extern "C" void kernel_launch(void* const* d_in, const int* in_sizes, int n_in,
                              void* d_out, int out_size, void* d_ws, size_t ws_size,
                              hipStream_t stream) {
    const float* H    = (const float*)d_in[0];
    const float* Y    = (const float*)d_in[1];
    const float* W1   = (const float*)d_in[2];
    const float* b1   = (const float*)d_in[3];
    const float* W2   = (const float*)d_in[4];
    // d_in[5] = attn_b2: softmax-shift-invariant, unused
    const float* Wih  = (const float*)d_in[6];
    const float* Whh  = (const float*)d_in[7];
    const float* bih  = (const float*)d_in[8];
    const float* bhh  = (const float*)d_in[9];
    const float* fcW  = (const float*)d_in[10];
    const float* fcb  = (const float*)d_in[11];
    const float* fcfW = (const float*)d_in[12];
    const float* fcfb = (const float*)d_in[13];

    char* ws = (char*)d_ws;
    __half* HWh = (__half*)ws;                            // 32 MB
    __half* HhT = (__half*)(ws + 33554432);               // 32 MB
    __half* W1m = (__half*)(ws + 2 * 33554432);           // 64 KB
    __half* WTm = (__half*)(ws + 2 * 33554432 + 65536);   // 128 KB
    float* out = (float*)d_out;

    prep_hw<<<BN * TN / 16, 256, 0, stream>>>(H, W1, b1, HWh);
    prep_ht<<<BN, 256, 0, stream>>>(H, HhT);
    prep_w1m<<<128, 256, 0, stream>>>(W1, W1m);
    prep_wtm<<<256, 256, 0, stream>>>(Whh, WTm);
    decoder_scan<<<NBLK, 512, 0, stream>>>(Y, W2, Wih, bih, bhh,
                                           fcW, fcb, fcfW, fcfb,
                                           HWh, HhT, (const uint4*)W1m,
                                           (const uint4*)WTm, out);
}

// Round 9
// 468.309 us; speedup vs baseline: 3.0234x; 1.0520x over previous
//
#include <hip/hip_runtime.h>
#include <hip/hip_fp16.h>

#define TN 64
#define BN 2048
#define G 8
#define NBLK (BN / G)   // 256 blocks x 512 threads, 1 block/CU, SINGLE round

// KK = -2/ln2. Attention tanh via sigma(2x) = 1/(1 + 2^(KK*x)), exponential
// FACTORED: 2^(KK*(hw+p)) = E*P; E = 2^(KK*hw) precomputed (prep_hw),
// P = 2^(KK*p) once per step per f (region A). e-loop: hfma2 + h2rcp only.
// ctx is NEVER materialized per step: ctx.fcW = (sum ex*q)/(sum ex) with
// q[t] = H[t,:].fcW[0:128] precomputed; epilogue ctx.fcfW[128:256] likewise
// via r[t] = H[t,:].fcfW[128:256]. (Softmax shift-invariance + linearity.)
#define KK (-2.88539008f)

typedef _Float16 h2v __attribute__((ext_vector_type(2)));
typedef _Float16 half8 __attribute__((ext_vector_type(8)));
typedef float float4v __attribute__((ext_vector_type(4)));

union FU {
    uint4 u;
    half8 h8;
    h2v hv[4];
    __half2 h2[4];
    _Float16 f16[8];
};
union H2U { __half2 h; h2v v; };

#define LAUNDER4(v) asm volatile("" : "+v"((v).x), "+v"((v).y), "+v"((v).z), "+v"((v).w))

__device__ __forceinline__ float fast_sigmoid(float x) {
    return __builtin_amdgcn_rcpf(1.f + __expf(-x));
}
__device__ __forceinline__ float fast_tanhf(float x) {
    return fmaf(2.f, fast_sigmoid(2.f * x), -1.f);
}
__device__ __forceinline__ float fdot2f(__half2 a, __half2 b, float c) {
    H2U ua; ua.h = a; H2U ub; ub.h = b;
    return __builtin_amdgcn_fdot2(ua.v, ub.v, c, false);
}

// wave64 sum via DPP (row_shr 1/2/4/8 + row_bcast15/31), result broadcast from
// lane 63. Independent calls interleave their chains (ILP).
__device__ __forceinline__ float wave_sum64(float x) {
    union FI { float f; int i; };
    FI a, b; a.f = x;
    b.i = __builtin_amdgcn_update_dpp(0, a.i, 0x111, 0xf, 0xf, true); a.f += b.f;
    b.i = __builtin_amdgcn_update_dpp(0, a.i, 0x112, 0xf, 0xf, true); a.f += b.f;
    b.i = __builtin_amdgcn_update_dpp(0, a.i, 0x114, 0xf, 0xf, true); a.f += b.f;
    b.i = __builtin_amdgcn_update_dpp(0, a.i, 0x118, 0xf, 0xf, true); a.f += b.f;
    b.i = __builtin_amdgcn_update_dpp(0, a.i, 0x142, 0xf, 0xf, true); a.f += b.f;
    b.i = __builtin_amdgcn_update_dpp(0, a.i, 0x143, 0xf, 0xf, true); a.f += b.f;
    FI r; r.i = __builtin_amdgcn_readlane(a.i, 63);
    return r.f;
}

// dc swizzled offset (halves): chunk c of row g at slot (c&16)|((c&15)^g)
__device__ __forceinline__ int dc_off(int g, int e) {
    int c = e >> 3;
    int slot = (c & 16) | ((c & 15) ^ (g & 15));
    return g * 256 + slot * 8 + (e & 7);
}

// ---- HW[b,t,f] = E = 2^(KK*(H[b,t,:] @ W1[256:384,:] + b1)), fp16 [b*T+t][128]
__global__ __launch_bounds__(256) void prep_hw(
    const float* __restrict__ H, const float* __restrict__ W1,
    const float* __restrict__ b1, __half* __restrict__ HWh) {
    __shared__ float sH[16 * 128];
    const int i = threadIdx.x;
    const long r0 = (long)blockIdx.x * 16;
    #pragma unroll
    for (int u = 0; u < 8; ++u) sH[u * 256 + i] = H[r0 * 128 + u * 256 + i];
    __syncthreads();
    const int f = i & 127;
    const int half_ = i >> 7;
    float acc[8];
    float bb = b1[f];
    #pragma unroll
    for (int u = 0; u < 8; ++u) acc[u] = bb;
    #pragma unroll 4
    for (int h = 0; h < 128; ++h) {
        float wv = W1[(256 + h) * 128 + f];
        #pragma unroll
        for (int u = 0; u < 8; ++u)
            acc[u] = fmaf(sH[(half_ + 2 * u) * 128 + h], wv, acc[u]);
    }
    #pragma unroll
    for (int u = 0; u < 8; ++u) {
        float z = fminf(fmaxf(KK * acc[u], -14.f), 14.f);
        HWh[(r0 + half_ + 2 * u) * 128 + f] = __float2half(exp2f(z));
    }
}

// ---- qr[b*64+t] = { H[b,t,:].fcW[0:128], H[b,t,:].fcfW[128:256] } (fp32)
__global__ __launch_bounds__(256) void prep_qr(
    const float* __restrict__ H, const float* __restrict__ fcW,
    const float* __restrict__ fcfW, float2* __restrict__ qr) {
    __shared__ float sh[64 * 128];
    const int b = blockIdx.x, i = threadIdx.x;
    #pragma unroll
    for (int u = 0; u < 32; ++u) sh[u * 256 + i] = H[(long)b * 8192 + u * 256 + i];
    __syncthreads();
    if (i < 128) {
        const int t = i >> 1, which = i & 1;
        const float* w = which ? (fcfW + 128) : fcW;
        float sum = 0.f;
        #pragma unroll 4
        for (int f = 0; f < 128; ++f) sum = fmaf(sh[t * 128 + f], w[f], sum);
        ((float*)(qr + (size_t)b * 64 + t))[which] = sum;
    }
}

// ---- W1m: KK * W1[0:256][:] in MFMA B-frag layout (frag fi = w*8+kt)
__global__ __launch_bounds__(256) void prep_w1m(
    const float* __restrict__ W1, __half* __restrict__ W1m) {
    int tid = blockIdx.x * 256 + threadIdx.x;   // 32768
    int fi = tid >> 9, rem = tid & 511, l = rem >> 3, j = rem & 7;
    int w = fi >> 3, kt = fi & 7;
    int row = kt * 32 + (l >> 4) * 8 + j;
    int col = w * 16 + (l & 15);
    W1m[tid] = __float2half(KK * W1[row * 128 + col]);
}

// ---- WTm: Whh^T in MFMA B-frag layout (frag fi = nt*4+kt)
__global__ __launch_bounds__(256) void prep_wtm(
    const float* __restrict__ Whh, __half* __restrict__ WTm) {
    int tid = blockIdx.x * 256 + threadIdx.x;   // 65536
    int fi = tid >> 9, rem = tid & 511, l = rem >> 3, j = rem & 7;
    int nt = fi >> 2, kt = fi & 3;
    int k = kt * 32 + (l >> 4) * 8 + j;
    int n = nt * 16 + (l & 15);
    WTm[tid] = __float2half(Whh[n * 128 + k]);
}

struct SMem {
    __half dc[G * 256];        //   4096 B  dc_off swizzle
    float sg[G * 512];         //  16384 B  gates [g][512]
    __half spH[G * 128];       //   2048 B  P = 2^(KK*p) fp16 [g][128]
    __half w2h[128];           //    256 B  (pre-scaled: -KK*W2)
    float sY[G * 64];          //   2048 B
};                             // ~24832 B total (ht tile eliminated)

__global__ __launch_bounds__(512, 2) void decoder_scan(
    const float* __restrict__ Y, const float* __restrict__ W2,
    const float* __restrict__ Wih, const float* __restrict__ bih,
    const float* __restrict__ bhh, const float* __restrict__ fcW,
    const float* __restrict__ fcb, const float* __restrict__ fcfW,
    const float* __restrict__ fcfb,
    const __half* __restrict__ HWh, const float2* __restrict__ qr,
    const uint4* __restrict__ W1m4, const uint4* __restrict__ WTm4,
    float* __restrict__ out) {

    __shared__ SMem sm;

    const int tid = threadIdx.x;
    const int bbase = blockIdx.x * G;
    const int lane = tid & 63;
    const int wv = tid >> 6;            // wave id == batch-group g
    const int g = wv;

    // ---- init ----
    // E[g][t=lane][0..127] -> laundered registers (64 VGPR)
    uint4 hwr[16];
    {
        const uint4* src = (const uint4*)(HWh + (((long)(bbase + g) * TN + lane) * 128));
        #pragma unroll
        for (int u = 0; u < 16; ++u) { hwr[u] = src[u]; LAUNDER4(hwr[u]); }
    }
    // W1 B-frags (8 = 32 regs), WhhT B-frags (16 = 64 regs), laundered (AGPR-ok)
    uint4 w1f[8];
    #pragma unroll
    for (int kt = 0; kt < 8; ++kt) {
        w1f[kt] = W1m4[(size_t)(wv * 8 + kt) * 64 + lane];
        LAUNDER4(w1f[kt]);
    }
    uint4 wtf[16];
    #pragma unroll
    for (int q = 0; q < 16; ++q) {
        wtf[q] = WTm4[(size_t)(wv * 16 + q) * 64 + lane];
        LAUNDER4(wtf[q]);
    }
    ((unsigned*)sm.dc)[tid] = 0u;
    ((unsigned*)sm.dc)[512 + tid] = 0u;
    if (tid < 128) sm.w2h[tid] = __float2half(-KK * W2[tid]);  // 2*log2e*W2
    sm.sY[tid] = Y[(long)bbase * TN + tid];
    // per-lane scan projections: q (y~ path), r (epilogue ctx path)
    const float2 qrv = qr[(size_t)(bbase + g) * TN + lane];
    const float qv = qrv.x, rv = qrv.y;
    float c0 = 0.f, c1 = 0.f;
    float dAr = 0.f, dBr = 0.f;        // final-step d (epilogue)
    float ctxc = 0.f;                  // final-step ctx.fcfW[128:256] (scalar)
    float wihA[4], wihB[4], bsA[4], bsB[4];
    #pragma unroll
    for (int q = 0; q < 4; ++q) {
        wihA[q] = Wih[q * 128 + lane];
        wihB[q] = Wih[q * 128 + 64 + lane];
        bsA[q] = bih[q * 128 + lane] + bhh[q * 128 + lane];
        bsB[q] = bih[q * 128 + 64 + lane] + bhh[q * 128 + 64 + lane];
    }
    const float fcw2 = fcW[128], fcb0 = fcb[0];
    __syncthreads();

    #pragma unroll 1
    for (int s = 0; s < TN; ++s) {
        // ==== region A: p + gates MFMAs (rows = g, 8/16 real) ====
        // All fragment registers (a4, pacc, gacc) die before b1 (R5 lesson).
        {
            const int m = lane & 15, q = lane >> 4;
            FU a4[4];
            #pragma unroll
            for (int kt = 0; kt < 4; ++kt) {
                int slot = ((kt * 4 + q) & 15) ^ m;      // d-part chunks
                a4[kt].u = *(const uint4*)&sm.dc[m * 256 + slot * 8];
            }
            float4v pacc1 = (float4v){0.f, 0.f, 0.f, 0.f};
            float4v pacc2 = (float4v){0.f, 0.f, 0.f, 0.f};
            float4v gacc[4];
            #pragma unroll
            for (int i = 0; i < 4; ++i) gacc[i] = (float4v){0.f, 0.f, 0.f, 0.f};
            #pragma unroll
            for (int kt = 0; kt < 4; ++kt) {
                FU b; b.u = w1f[kt];
                pacc1 = __builtin_amdgcn_mfma_f32_16x16x32_f16(a4[kt].h8, b.h8, pacc1, 0, 0, 0);
            }
            #pragma unroll
            for (int i = 0; i < 4; ++i) {
                #pragma unroll
                for (int kt = 0; kt < 4; ++kt) {
                    FU b; b.u = wtf[i * 4 + kt];
                    gacc[i] = __builtin_amdgcn_mfma_f32_16x16x32_f16(a4[kt].h8, b.h8, gacc[i], 0, 0, 0);
                }
            }
            #pragma unroll
            for (int kt = 0; kt < 4; ++kt) {
                int slot = 16 | (((kt * 4 + q) & 15) ^ m);   // c-part chunks
                FU a; a.u = *(const uint4*)&sm.dc[m * 256 + slot * 8];
                FU b; b.u = w1f[4 + kt];
                pacc2 = __builtin_amdgcn_mfma_f32_16x16x32_f16(a.h8, b.h8, pacc2, 0, 0, 0);
            }
            if (lane < 32) {
                const int row0 = (lane >> 4) * 4, col = lane & 15;
                #pragma unroll
                for (int r = 0; r < 4; ++r) {
                    // P = 2^(KK*p), clamped exponent (pacc is already KK-scaled)
                    float pv = fminf(fmaxf(pacc1[r] + pacc2[r], -14.f), 14.f);
                    sm.spH[(row0 + r) * 128 + wv * 16 + col] = __float2half(exp2f(pv));
                }
                #pragma unroll
                for (int i = 0; i < 4; ++i) {
                    #pragma unroll
                    for (int r = 0; r < 4; ++r)
                        sm.sg[(row0 + r) * 512 + (wv * 4 + i) * 16 + col] = gacc[i][r];
                }
            }
        }
        __syncthreads();   // b1

        // ==== phase 3: wave-local: e -> softmax sums -> y~ -> LSTM ====
        {
            // e-loop: sigma = rcp(1 + E*P); ea[t=lane] = sum_f (-KK)*w2[f]*sigma
            const uint4* pH = (const uint4*)&sm.spH[g * 128];
            const __half2* w2b = (const __half2*)sm.w2h;
            const __half2 one2 = __float2half2_rn(1.f);
            float ea0 = 0.f, ea1 = 0.f, ea2 = 0.f, ea3 = 0.f;
            #pragma unroll
            for (int u = 0; u < 16; ++u) {
                FU hw; hw.u = hwr[u];
                FU pp; pp.u = pH[u];
                __half2 th0 = h2rcp(__hfma2(hw.h2[0], pp.h2[0], one2));
                __half2 th1 = h2rcp(__hfma2(hw.h2[1], pp.h2[1], one2));
                __half2 th2 = h2rcp(__hfma2(hw.h2[2], pp.h2[2], one2));
                __half2 th3 = h2rcp(__hfma2(hw.h2[3], pp.h2[3], one2));
                ea0 = fdot2f(th0, w2b[u * 4 + 0], ea0);
                ea1 = fdot2f(th1, w2b[u * 4 + 1], ea1);
                ea2 = fdot2f(th2, w2b[u * 4 + 2], ea2);
                ea3 = fdot2f(th3, w2b[u * 4 + 3], ea3);
            }
            float ea = (ea0 + ea1) + (ea2 + ea3);
            // softmax-weighted scalars: y~ ctx-part = (sum ex*q)/(sum ex).
            // Two independent DPP chains interleave (ILP); no beta, no ctx loop.
            float ex = exp2f(ea);
            float ssum = wave_sum64(ex);
            float sq = wave_sum64(ex * qv);
            float rs = __builtin_amdgcn_rcpf(ssum);
            if (s == TN - 1)
                ctxc = wave_sum64(ex * rv) * rs;       // epilogue ctx.fcfW part
            float syg = fmaf(sq, rs, fmaf(sm.sY[g * 64 + s], fcw2, fcb0));
            // LSTM cell for feats lane and lane+64
            float a0A = sm.sg[g * 512 + lane]       + fmaf(syg, wihA[0], bsA[0]);
            float a1A = sm.sg[g * 512 + 128 + lane] + fmaf(syg, wihA[1], bsA[1]);
            float a2A = sm.sg[g * 512 + 256 + lane] + fmaf(syg, wihA[2], bsA[2]);
            float a3A = sm.sg[g * 512 + 384 + lane] + fmaf(syg, wihA[3], bsA[3]);
            float a0B = sm.sg[g * 512 + 64 + lane]  + fmaf(syg, wihB[0], bsB[0]);
            float a1B = sm.sg[g * 512 + 192 + lane] + fmaf(syg, wihB[1], bsB[1]);
            float a2B = sm.sg[g * 512 + 320 + lane] + fmaf(syg, wihB[2], bsB[2]);
            float a3B = sm.sg[g * 512 + 448 + lane] + fmaf(syg, wihB[3], bsB[3]);
            float iA = fast_sigmoid(a0A), fA = fast_sigmoid(a1A);
            float gA = fast_tanhf(a2A),  oA = fast_sigmoid(a3A);
            c0 = fmaf(fA, c0, iA * gA);
            dAr = oA * fast_tanhf(c0);
            float iB = fast_sigmoid(a0B), fB = fast_sigmoid(a1B);
            float gB = fast_tanhf(a2B),  oB = fast_sigmoid(a3B);
            c1 = fmaf(fB, c1, iB * gB);
            dBr = oB * fast_tanhf(c1);
            sm.dc[dc_off(g, lane)] = __float2half(dAr);
            sm.dc[dc_off(g, 64 + lane)] = __float2half(dBr);
            sm.dc[dc_off(g, 128 + lane)] = __float2half(c0);
            sm.dc[dc_off(g, 192 + lane)] = __float2half(c1);
        }
        __syncthreads();   // b2 (step end)
    }

    // ---- epilogue: d from registers (fp32), ctx part via precomputed r ----
    {
        float part = dAr * fcfW[lane] + dBr * fcfW[64 + lane];
        float tot = wave_sum64(part);
        if (lane == 0) out[bbase + g] = tot + ctxc + fcfb[0];
    }
}

extern "C" void kernel_launch(void* const* d_in, const int* in_sizes, int n_in,
                              void* d_out, int out_size, void* d_ws, size_t ws_size,
                              hipStream_t stream) {
    const float* H    = (const float*)d_in[0];
    const float* Y    = (const float*)d_in[1];
    const float* W1   = (const float*)d_in[2];
    const float* b1   = (const float*)d_in[3];
    const float* W2   = (const float*)d_in[4];
    // d_in[5] = attn_b2: softmax-shift-invariant, unused
    const float* Wih  = (const float*)d_in[6];
    const float* Whh  = (const float*)d_in[7];
    const float* bih  = (const float*)d_in[8];
    const float* bhh  = (const float*)d_in[9];
    const float* fcW  = (const float*)d_in[10];
    const float* fcb  = (const float*)d_in[11];
    const float* fcfW = (const float*)d_in[12];
    const float* fcfb = (const float*)d_in[13];

    char* ws = (char*)d_ws;
    __half* HWh = (__half*)ws;                            // 32 MB
    float2* qrp = (float2*)(ws + 33554432);               // 1 MB (old HhT slot)
    __half* W1m = (__half*)(ws + 2 * 33554432);           // 64 KB
    __half* WTm = (__half*)(ws + 2 * 33554432 + 65536);   // 128 KB
    float* out = (float*)d_out;

    prep_hw<<<BN * TN / 16, 256, 0, stream>>>(H, W1, b1, HWh);
    prep_qr<<<BN, 256, 0, stream>>>(H, fcW, fcfW, qrp);
    prep_w1m<<<128, 256, 0, stream>>>(W1, W1m);
    prep_wtm<<<256, 256, 0, stream>>>(Whh, WTm);
    decoder_scan<<<NBLK, 512, 0, stream>>>(Y, W2, Wih, bih, bhh,
                                           fcW, fcb, fcfW, fcfb,
                                           HWh, qrp, (const uint4*)W1m,
                                           (const uint4*)WTm, out);
}

// Round 10
// 395.334 us; speedup vs baseline: 3.5815x; 1.1846x over previous
//
#include <hip/hip_runtime.h>
#include <hip/hip_fp16.h>

#define TN 64
#define BN 2048
#define G 8
#define NBLK (BN / G)   // 256 blocks x 512 threads, 1 block/CU, SINGLE round

// KK = -2/ln2. Attention tanh via sigma(2x) = 1/(1 + 2^(KK*x)), exponential
// FACTORED: 2^(KK*(hw+p)) = E*P; E = 2^(KK*hw) precomputed (prep_hwqr, MFMA),
// P = 2^(KK*p) once per step per f (region A). e-loop: hfma2 + h2rcp only.
// ctx is NEVER materialized per step: ctx.fcW = (sum ex*q)/(sum ex) with
// q[t] = H[t,:].fcW[0:128] precomputed; epilogue ctx.fcfW[128:256] likewise
// via r[t] = H[t,:].fcfW[128:256]. (Softmax shift-invariance + linearity.)
#define KK (-2.88539008f)

typedef _Float16 h2v __attribute__((ext_vector_type(2)));
typedef _Float16 half8 __attribute__((ext_vector_type(8)));
typedef float float4v __attribute__((ext_vector_type(4)));

union FU {
    uint4 u;
    half8 h8;
    h2v hv[4];
    __half2 h2[4];
    _Float16 f16[8];
};
union H2U { __half2 h; h2v v; };

#define LAUNDER4(v) asm volatile("" : "+v"((v).x), "+v"((v).y), "+v"((v).z), "+v"((v).w))

__device__ __forceinline__ float fast_sigmoid(float x) {
    return __builtin_amdgcn_rcpf(1.f + __expf(-x));
}
__device__ __forceinline__ float fast_tanhf(float x) {
    return fmaf(2.f, fast_sigmoid(2.f * x), -1.f);
}
__device__ __forceinline__ float fdot2f(__half2 a, __half2 b, float c) {
    H2U ua; ua.h = a; H2U ub; ub.h = b;
    return __builtin_amdgcn_fdot2(ua.v, ub.v, c, false);
}

// wave64 sum via DPP (row_shr 1/2/4/8 + row_bcast15/31), result broadcast from
// lane 63. Independent calls interleave their chains (ILP).
__device__ __forceinline__ float wave_sum64(float x) {
    union FI { float f; int i; };
    FI a, b; a.f = x;
    b.i = __builtin_amdgcn_update_dpp(0, a.i, 0x111, 0xf, 0xf, true); a.f += b.f;
    b.i = __builtin_amdgcn_update_dpp(0, a.i, 0x112, 0xf, 0xf, true); a.f += b.f;
    b.i = __builtin_amdgcn_update_dpp(0, a.i, 0x114, 0xf, 0xf, true); a.f += b.f;
    b.i = __builtin_amdgcn_update_dpp(0, a.i, 0x118, 0xf, 0xf, true); a.f += b.f;
    b.i = __builtin_amdgcn_update_dpp(0, a.i, 0x142, 0xf, 0xf, true); a.f += b.f;
    b.i = __builtin_amdgcn_update_dpp(0, a.i, 0x143, 0xf, 0xf, true); a.f += b.f;
    FI r; r.i = __builtin_amdgcn_readlane(a.i, 63);
    return r.f;
}

// dc swizzled offset (halves): chunk c of row g at slot (c&16)|((c&15)^g)
__device__ __forceinline__ int dc_off(int g, int e) {
    int c = e >> 3;
    int slot = (c & 16) | ((c & 15) ^ (g & 15));
    return g * 256 + slot * 8 + (e & 7);
}

#define PPAD 136   // padded row stride (halves) for conflict-minimal frag reads

// ---- MFMA prep: E = 2^(KK*(H@W1[256:384]+b1)) fp16 [row][128]  AND
//      qr[row] = { H[row,:].fcW[0:128], H[row,:].fcfW[128:256] } fp32.
// One H pass; frag layouts identical to decoder (A: lane(m=l&15,q=l>>4) holds
// row m, k=kt*32+q*8+j; C: row=(l>>4)*4+r, col=l&15).
__global__ __launch_bounds__(512) void prep_hwqr(
    const float* __restrict__ H, const float* __restrict__ W1,
    const float* __restrict__ b1, const float* __restrict__ fcW,
    const float* __restrict__ fcfW,
    __half* __restrict__ HWh, float2* __restrict__ qr) {
    __shared__ __half Hl[128 * PPAD];   // 34816 B
    const int tid = threadIdx.x;
    const long r0 = (long)blockIdx.x * 128;   // 1024 blocks x 128 rows
    // stage H rows (fp32 -> fp16), padded
    {
        const int row = tid >> 2, cb = (tid & 3) * 32;
        const float4* src = (const float4*)(H + (r0 + row) * 128 + cb);
        uint4 w[4];
        #pragma unroll
        for (int v = 0; v < 4; ++v) {
            float4 a = src[2 * v], b = src[2 * v + 1];
            FU f;
            f.hv[0] = (h2v){(_Float16)a.x, (_Float16)a.y};
            f.hv[1] = (h2v){(_Float16)a.z, (_Float16)a.w};
            f.hv[2] = (h2v){(_Float16)b.x, (_Float16)b.y};
            f.hv[3] = (h2v){(_Float16)b.z, (_Float16)b.w};
            w[v] = f.u;
        }
        uint4* dst = (uint4*)&Hl[row * PPAD + cb];
        #pragma unroll
        for (int v = 0; v < 4; ++v) dst[v] = w[v];
    }
    const int lane = tid & 63, wv = tid >> 6;   // 8 waves
    const int n = lane & 15, q = lane >> 4;
    // B-frags: wave wv -> W1c col-tile wv (KK folded); wave 0 also qr tile
    uint4 bw[4];
    #pragma unroll
    for (int kt = 0; kt < 4; ++kt) {
        FU f;
        #pragma unroll
        for (int j = 0; j < 8; ++j) {
            int k = kt * 32 + q * 8 + j;
            f.f16[j] = (_Float16)(KK * W1[(256 + k) * 128 + wv * 16 + n]);
        }
        bw[kt] = f.u;
    }
    const float b1v = KK * b1[wv * 16 + n];
    uint4 bq[4];
    if (wv == 0) {
        #pragma unroll
        for (int kt = 0; kt < 4; ++kt) {
            FU f;
            #pragma unroll
            for (int j = 0; j < 8; ++j) {
                int k = kt * 32 + q * 8 + j;
                float v = (n == 0) ? fcW[k] : (n == 1 ? fcfW[128 + k] : 0.f);
                f.f16[j] = (_Float16)v;
            }
            bq[kt] = f.u;
        }
    }
    __syncthreads();

    #pragma unroll 2
    for (int rg = 0; rg < 8; ++rg) {
        FU a4[4];
        #pragma unroll
        for (int kt = 0; kt < 4; ++kt)
            a4[kt].u = *(const uint4*)&Hl[(rg * 16 + n) * PPAD + kt * 32 + q * 8];
        float4v acc = (float4v){b1v, b1v, b1v, b1v};
        #pragma unroll
        for (int kt = 0; kt < 4; ++kt) {
            FU b; b.u = bw[kt];
            acc = __builtin_amdgcn_mfma_f32_16x16x32_f16(a4[kt].h8, b.h8, acc, 0, 0, 0);
        }
        const long rowb = r0 + rg * 16 + q * 4;
        #pragma unroll
        for (int r = 0; r < 4; ++r) {
            float z = fminf(fmaxf(acc[r], -14.f), 14.f);
            HWh[(rowb + r) * 128 + wv * 16 + n] = __float2half(exp2f(z));
        }
        if (wv == 0) {
            float4v qa = (float4v){0.f, 0.f, 0.f, 0.f};
            #pragma unroll
            for (int kt = 0; kt < 4; ++kt) {
                FU b; b.u = bq[kt];
                qa = __builtin_amdgcn_mfma_f32_16x16x32_f16(a4[kt].h8, b.h8, qa, 0, 0, 0);
            }
            if (n < 2) {
                #pragma unroll
                for (int r = 0; r < 4; ++r)
                    ((float*)(qr + (rowb + r)))[n] = qa[r];
            }
        }
    }
}

// ---- merged weight-frag prep: W1m (KK*W1[0:256], frag fi = w*8+kt) and
//      WTm (Whh^T, frag fi = nt*4+kt)
__global__ __launch_bounds__(256) void prep_wm(
    const float* __restrict__ W1, const float* __restrict__ Whh,
    __half* __restrict__ W1m, __half* __restrict__ WTm) {
    const int bid = blockIdx.x;
    if (bid < 128) {
        int tid = bid * 256 + threadIdx.x;   // 32768
        int fi = tid >> 9, rem = tid & 511, l = rem >> 3, j = rem & 7;
        int w = fi >> 3, kt = fi & 7;
        int row = kt * 32 + (l >> 4) * 8 + j;
        int col = w * 16 + (l & 15);
        W1m[tid] = __float2half(KK * W1[row * 128 + col]);
    } else {
        int tid = (bid - 128) * 256 + threadIdx.x;   // 65536
        int fi = tid >> 9, rem = tid & 511, l = rem >> 3, j = rem & 7;
        int nt = fi >> 2, kt = fi & 3;
        int k = kt * 32 + (l >> 4) * 8 + j;
        int n = nt * 16 + (l & 15);
        WTm[tid] = __float2half(Whh[n * 128 + k]);
    }
}

struct SMem {
    __half dc[G * 256];        //   4096 B  dc_off swizzle
    float sg[G * 512];         //  16384 B  gates [g][512]
    __half spH[G * 128];       //   2048 B  P = 2^(KK*p) fp16 [g][128]
    __half w2h[128];           //    256 B  (pre-scaled: -KK*W2)
    float sY[G * 64];          //   2048 B
};                             // ~24832 B total

__global__ __launch_bounds__(512, 2) void decoder_scan(
    const float* __restrict__ Y, const float* __restrict__ W2,
    const float* __restrict__ Wih, const float* __restrict__ bih,
    const float* __restrict__ bhh, const float* __restrict__ fcW,
    const float* __restrict__ fcb, const float* __restrict__ fcfW,
    const float* __restrict__ fcfb,
    const __half* __restrict__ HWh, const float2* __restrict__ qr,
    const uint4* __restrict__ W1m4, const uint4* __restrict__ WTm4,
    float* __restrict__ out) {

    __shared__ SMem sm;

    const int tid = threadIdx.x;
    const int bbase = blockIdx.x * G;
    const int lane = tid & 63;
    const int wv = tid >> 6;            // wave id == batch-group g
    const int g = wv;

    // ---- init ----
    // E[g][t=lane][0..127] -> laundered registers (64 VGPR)
    uint4 hwr[16];
    {
        const uint4* src = (const uint4*)(HWh + (((long)(bbase + g) * TN + lane) * 128));
        #pragma unroll
        for (int u = 0; u < 16; ++u) { hwr[u] = src[u]; LAUNDER4(hwr[u]); }
    }
    // W1 B-frags (8 = 32 regs), WhhT B-frags (16 = 64 regs), laundered (AGPR-ok)
    uint4 w1f[8];
    #pragma unroll
    for (int kt = 0; kt < 8; ++kt) {
        w1f[kt] = W1m4[(size_t)(wv * 8 + kt) * 64 + lane];
        LAUNDER4(w1f[kt]);
    }
    uint4 wtf[16];
    #pragma unroll
    for (int q = 0; q < 16; ++q) {
        wtf[q] = WTm4[(size_t)(wv * 16 + q) * 64 + lane];
        LAUNDER4(wtf[q]);
    }
    ((unsigned*)sm.dc)[tid] = 0u;
    ((unsigned*)sm.dc)[512 + tid] = 0u;
    if (tid < 128) sm.w2h[tid] = __float2half(-KK * W2[tid]);  // 2*log2e*W2
    sm.sY[tid] = Y[(long)bbase * TN + tid];
    // per-lane scan projections: q (y~ path), r (epilogue ctx path)
    const float2 qrv = qr[(size_t)(bbase + g) * TN + lane];
    const float qv = qrv.x, rv = qrv.y;
    float c0 = 0.f, c1 = 0.f;
    float dAr = 0.f, dBr = 0.f;        // final-step d (epilogue)
    float ctxc = 0.f;                  // final-step ctx.fcfW[128:256] (scalar)
    float wihA[4], wihB[4], bsA[4], bsB[4];
    #pragma unroll
    for (int q = 0; q < 4; ++q) {
        wihA[q] = Wih[q * 128 + lane];
        wihB[q] = Wih[q * 128 + 64 + lane];
        bsA[q] = bih[q * 128 + lane] + bhh[q * 128 + lane];
        bsB[q] = bih[q * 128 + 64 + lane] + bhh[q * 128 + 64 + lane];
    }
    const float fcw2 = fcW[128], fcb0 = fcb[0];
    __syncthreads();

    #pragma unroll 1
    for (int s = 0; s < TN; ++s) {
        // ==== region A: p + gates MFMAs (rows = g, 8/16 real) ====
        // All fragment registers (a4, pacc, gacc) die before b1 (R5 lesson).
        {
            const int m = lane & 15, q = lane >> 4;
            FU a4[4];
            #pragma unroll
            for (int kt = 0; kt < 4; ++kt) {
                int slot = ((kt * 4 + q) & 15) ^ m;      // d-part chunks
                a4[kt].u = *(const uint4*)&sm.dc[m * 256 + slot * 8];
            }
            float4v pacc1 = (float4v){0.f, 0.f, 0.f, 0.f};
            float4v pacc2 = (float4v){0.f, 0.f, 0.f, 0.f};
            float4v gacc[4];
            #pragma unroll
            for (int i = 0; i < 4; ++i) gacc[i] = (float4v){0.f, 0.f, 0.f, 0.f};
            #pragma unroll
            for (int kt = 0; kt < 4; ++kt) {
                FU b; b.u = w1f[kt];
                pacc1 = __builtin_amdgcn_mfma_f32_16x16x32_f16(a4[kt].h8, b.h8, pacc1, 0, 0, 0);
            }
            #pragma unroll
            for (int i = 0; i < 4; ++i) {
                #pragma unroll
                for (int kt = 0; kt < 4; ++kt) {
                    FU b; b.u = wtf[i * 4 + kt];
                    gacc[i] = __builtin_amdgcn_mfma_f32_16x16x32_f16(a4[kt].h8, b.h8, gacc[i], 0, 0, 0);
                }
            }
            #pragma unroll
            for (int kt = 0; kt < 4; ++kt) {
                int slot = 16 | (((kt * 4 + q) & 15) ^ m);   // c-part chunks
                FU a; a.u = *(const uint4*)&sm.dc[m * 256 + slot * 8];
                FU b; b.u = w1f[4 + kt];
                pacc2 = __builtin_amdgcn_mfma_f32_16x16x32_f16(a.h8, b.h8, pacc2, 0, 0, 0);
            }
            if (lane < 32) {
                const int row0 = (lane >> 4) * 4, col = lane & 15;
                #pragma unroll
                for (int r = 0; r < 4; ++r) {
                    // P = 2^(KK*p), clamped exponent (pacc is already KK-scaled)
                    float pv = fminf(fmaxf(pacc1[r] + pacc2[r], -14.f), 14.f);
                    sm.spH[(row0 + r) * 128 + wv * 16 + col] = __float2half(exp2f(pv));
                }
                #pragma unroll
                for (int i = 0; i < 4; ++i) {
                    #pragma unroll
                    for (int r = 0; r < 4; ++r)
                        sm.sg[(row0 + r) * 512 + (wv * 4 + i) * 16 + col] = gacc[i][r];
                }
            }
        }
        __syncthreads();   // b1

        // ==== phase 3: wave-local: e -> softmax sums -> y~ -> LSTM ====
        {
            // e-loop: sigma = rcp(1 + E*P); ea[t=lane] = sum_f (-KK)*w2[f]*sigma
            const uint4* pH = (const uint4*)&sm.spH[g * 128];
            const __half2* w2b = (const __half2*)sm.w2h;
            const __half2 one2 = __float2half2_rn(1.f);
            float ea0 = 0.f, ea1 = 0.f, ea2 = 0.f, ea3 = 0.f;
            #pragma unroll
            for (int u = 0; u < 16; ++u) {
                FU hw; hw.u = hwr[u];
                FU pp; pp.u = pH[u];
                __half2 th0 = h2rcp(__hfma2(hw.h2[0], pp.h2[0], one2));
                __half2 th1 = h2rcp(__hfma2(hw.h2[1], pp.h2[1], one2));
                __half2 th2 = h2rcp(__hfma2(hw.h2[2], pp.h2[2], one2));
                __half2 th3 = h2rcp(__hfma2(hw.h2[3], pp.h2[3], one2));
                ea0 = fdot2f(th0, w2b[u * 4 + 0], ea0);
                ea1 = fdot2f(th1, w2b[u * 4 + 1], ea1);
                ea2 = fdot2f(th2, w2b[u * 4 + 2], ea2);
                ea3 = fdot2f(th3, w2b[u * 4 + 3], ea3);
            }
            float ea = (ea0 + ea1) + (ea2 + ea3);
            // softmax-weighted scalars: y~ ctx-part = (sum ex*q)/(sum ex).
            float ex = exp2f(ea);
            float ssum = wave_sum64(ex);
            float sq = wave_sum64(ex * qv);
            float rs = __builtin_amdgcn_rcpf(ssum);
            if (s == TN - 1)
                ctxc = wave_sum64(ex * rv) * rs;       // epilogue ctx.fcfW part
            float syg = fmaf(sq, rs, fmaf(sm.sY[g * 64 + s], fcw2, fcb0));
            // LSTM cell for feats lane and lane+64
            float a0A = sm.sg[g * 512 + lane]       + fmaf(syg, wihA[0], bsA[0]);
            float a1A = sm.sg[g * 512 + 128 + lane] + fmaf(syg, wihA[1], bsA[1]);
            float a2A = sm.sg[g * 512 + 256 + lane] + fmaf(syg, wihA[2], bsA[2]);
            float a3A = sm.sg[g * 512 + 384 + lane] + fmaf(syg, wihA[3], bsA[3]);
            float a0B = sm.sg[g * 512 + 64 + lane]  + fmaf(syg, wihB[0], bsB[0]);
            float a1B = sm.sg[g * 512 + 192 + lane] + fmaf(syg, wihB[1], bsB[1]);
            float a2B = sm.sg[g * 512 + 320 + lane] + fmaf(syg, wihB[2], bsB[2]);
            float a3B = sm.sg[g * 512 + 448 + lane] + fmaf(syg, wihB[3], bsB[3]);
            float iA = fast_sigmoid(a0A), fA = fast_sigmoid(a1A);
            float gA = fast_tanhf(a2A),  oA = fast_sigmoid(a3A);
            c0 = fmaf(fA, c0, iA * gA);
            dAr = oA * fast_tanhf(c0);
            float iB = fast_sigmoid(a0B), fB = fast_sigmoid(a1B);
            float gB = fast_tanhf(a2B),  oB = fast_sigmoid(a3B);
            c1 = fmaf(fB, c1, iB * gB);
            dBr = oB * fast_tanhf(c1);
            sm.dc[dc_off(g, lane)] = __float2half(dAr);
            sm.dc[dc_off(g, 64 + lane)] = __float2half(dBr);
            sm.dc[dc_off(g, 128 + lane)] = __float2half(c0);
            sm.dc[dc_off(g, 192 + lane)] = __float2half(c1);
        }
        __syncthreads();   // b2 (step end)
    }

    // ---- epilogue: d from registers (fp32), ctx part via precomputed r ----
    {
        float part = dAr * fcfW[lane] + dBr * fcfW[64 + lane];
        float tot = wave_sum64(part);
        if (lane == 0) out[bbase + g] = tot + ctxc + fcfb[0];
    }
}

extern "C" void kernel_launch(void* const* d_in, const int* in_sizes, int n_in,
                              void* d_out, int out_size, void* d_ws, size_t ws_size,
                              hipStream_t stream) {
    const float* H    = (const float*)d_in[0];
    const float* Y    = (const float*)d_in[1];
    const float* W1   = (const float*)d_in[2];
    const float* b1   = (const float*)d_in[3];
    const float* W2   = (const float*)d_in[4];
    // d_in[5] = attn_b2: softmax-shift-invariant, unused
    const float* Wih  = (const float*)d_in[6];
    const float* Whh  = (const float*)d_in[7];
    const float* bih  = (const float*)d_in[8];
    const float* bhh  = (const float*)d_in[9];
    const float* fcW  = (const float*)d_in[10];
    const float* fcb  = (const float*)d_in[11];
    const float* fcfW = (const float*)d_in[12];
    const float* fcfb = (const float*)d_in[13];

    char* ws = (char*)d_ws;
    __half* HWh = (__half*)ws;                            // 32 MB
    float2* qrp = (float2*)(ws + 33554432);               // 1 MB
    __half* W1m = (__half*)(ws + 2 * 33554432);           // 64 KB
    __half* WTm = (__half*)(ws + 2 * 33554432 + 65536);   // 128 KB
    float* out = (float*)d_out;

    prep_hwqr<<<BN * TN / 128, 512, 0, stream>>>(H, W1, b1, fcW, fcfW, HWh, qrp);
    prep_wm<<<384, 256, 0, stream>>>(W1, Whh, W1m, WTm);
    decoder_scan<<<NBLK, 512, 0, stream>>>(Y, W2, Wih, bih, bhh,
                                           fcW, fcb, fcfW, fcfb,
                                           HWh, qrp, (const uint4*)W1m,
                                           (const uint4*)WTm, out);
}

// Round 12
// 370.529 us; speedup vs baseline: 3.8213x; 1.0669x over previous
//
#include <hip/hip_runtime.h>
#include <hip/hip_fp16.h>

#define TN 64
#define BN 2048
#define G 8
#define NBLK (BN / G)   // 256 blocks x 512 threads, 1 block/CU, fully fused

// KK = -2/ln2. Attention tanh via sigma(2x) = 1/(1 + 2^(KK*x)), exponential
// FACTORED: 2^(KK*(hw+p)) = E*P; E = 2^(KK*hw) computed in-block (MFMA),
// P = 2^(KK*p) once per step per f (region A). e-loop: hfma2 + h2rcp only.
// ctx never materialized: ctx.fcW = (sum ex*q)/(sum ex), q/r projections
// computed in-block. Single kernel: no HWh/qr HBM round trip, 1 launch.
#define KK (-2.88539008f)
#define PPAD 136   // H-stage row stride (halves): 16B-aligned, 2-way banks
#define EPAD 136   // E-chunk row stride (halves): 16B-aligned b128 reads

typedef _Float16 h2v __attribute__((ext_vector_type(2)));
typedef _Float16 half8 __attribute__((ext_vector_type(8)));
typedef float float4v __attribute__((ext_vector_type(4)));

union FU {
    uint4 u;
    half8 h8;
    h2v hv[4];
    __half2 h2[4];
    _Float16 f16[8];
};
union H2U { __half2 h; h2v v; };

#define LAUNDER4(v) asm volatile("" : "+v"((v).x), "+v"((v).y), "+v"((v).z), "+v"((v).w))

__device__ __forceinline__ float fast_sigmoid(float x) {
    return __builtin_amdgcn_rcpf(1.f + __expf(-x));
}
__device__ __forceinline__ float fast_tanhf(float x) {
    return fmaf(2.f, fast_sigmoid(2.f * x), -1.f);
}
__device__ __forceinline__ float fdot2f(__half2 a, __half2 b, float c) {
    H2U ua; ua.h = a; H2U ub; ub.h = b;
    return __builtin_amdgcn_fdot2(ua.v, ub.v, c, false);
}

// wave64 sum via DPP (row_shr 1/2/4/8 + row_bcast15/31), broadcast from lane 63.
__device__ __forceinline__ float wave_sum64(float x) {
    union FI { float f; int i; };
    FI a, b; a.f = x;
    b.i = __builtin_amdgcn_update_dpp(0, a.i, 0x111, 0xf, 0xf, true); a.f += b.f;
    b.i = __builtin_amdgcn_update_dpp(0, a.i, 0x112, 0xf, 0xf, true); a.f += b.f;
    b.i = __builtin_amdgcn_update_dpp(0, a.i, 0x114, 0xf, 0xf, true); a.f += b.f;
    b.i = __builtin_amdgcn_update_dpp(0, a.i, 0x118, 0xf, 0xf, true); a.f += b.f;
    b.i = __builtin_amdgcn_update_dpp(0, a.i, 0x142, 0xf, 0xf, true); a.f += b.f;
    b.i = __builtin_amdgcn_update_dpp(0, a.i, 0x143, 0xf, 0xf, true); a.f += b.f;
    FI r; r.i = __builtin_amdgcn_readlane(a.i, 63);
    return r.f;
}

// dc swizzled offset (halves): chunk c of row g at slot (c&16)|((c&15)^g)
__device__ __forceinline__ int dc_off(int g, int e) {
    int c = e >> 3;
    int slot = (c & 16) | ((c & 15) ^ (g & 15));
    return g * 256 + slot * 8 + (e & 7);
}

struct SMem {
    __half dc[G * 256];        //   4096 B  dc_off swizzle
    float sg[G * 512];         //  16384 B  gates [g][512]
    __half spH[G * 128];       //   2048 B  P = 2^(KK*p) fp16 [g][128]
    __half w2h[128];           //    256 B  (pre-scaled: -KK*W2)
    float sY[G * 64];          //   2048 B
};                             // 24832 B persistent

__global__ __launch_bounds__(512, 2) void decoder_scan(
    const float* __restrict__ H, const float* __restrict__ Y,
    const float* __restrict__ W1, const float* __restrict__ b1,
    const float* __restrict__ W2, const float* __restrict__ Wih,
    const float* __restrict__ Whh, const float* __restrict__ bih,
    const float* __restrict__ bhh, const float* __restrict__ fcW,
    const float* __restrict__ fcb, const float* __restrict__ fcfW,
    const float* __restrict__ fcfb, float* __restrict__ out) {

    __shared__ SMem sm;
    __shared__ __half Hst[128 * PPAD];   // 34816 B init scratch
    __shared__ __half Ech[128 * EPAD];   // 34816 B init scratch
    __shared__ float2 qbuf[128];         //  1024 B init scratch
                                         // total ~95.5 KB, 1 block/CU

    const int tid = threadIdx.x;
    const int bbase = blockIdx.x * G;
    const int lane = tid & 63;
    const int wv = tid >> 6;            // wave id == batch-group g
    const int g = wv;
    const int n16 = lane & 15, q4 = lane >> 4;

    // ==== init phase 1: E = 2^(KK*(H@W1c+b1)) + qr projections, in-block ====
    // B-frags (temps): wave wv -> W1c col-tile wv (KK folded); wave 0 also qr.
    uint4 bw[4];
    #pragma unroll
    for (int kt = 0; kt < 4; ++kt) {
        FU f;
        #pragma unroll
        for (int j = 0; j < 8; ++j) {
            int k = kt * 32 + q4 * 8 + j;
            f.f16[j] = (_Float16)(KK * W1[(256 + k) * 128 + wv * 16 + n16]);
        }
        bw[kt] = f.u;
    }
    const float b1v = KK * b1[wv * 16 + n16];
    uint4 bq[4];
    if (wv == 0) {
        #pragma unroll
        for (int kt = 0; kt < 4; ++kt) {
            FU f;
            #pragma unroll
            for (int j = 0; j < 8; ++j) {
                int k = kt * 32 + q4 * 8 + j;
                float v = (n16 == 0) ? fcW[k] : (n16 == 1 ? fcfW[128 + k] : 0.f);
                f.f16[j] = (_Float16)v;
            }
            bq[kt] = f.u;
        }
    }

    uint4 hwr[16];          // E[g][t=lane][0..127], filled in chunk g>>1
    float qv = 0.f, rv = 0.f;

    #pragma unroll 1
    for (int c = 0; c < 4; ++c) {
        // stage 128 H rows (2 batches) fp32 -> fp16, padded
        {
            const int row = tid >> 2, cb = (tid & 3) * 32;
            const float4* src = (const float4*)(
                H + ((long)bbase * TN + c * 128 + row) * 128 + cb);
            uint4 w[4];
            #pragma unroll
            for (int v = 0; v < 4; ++v) {
                float4 a = src[2 * v], b = src[2 * v + 1];
                FU f;
                f.hv[0] = (h2v){(_Float16)a.x, (_Float16)a.y};
                f.hv[1] = (h2v){(_Float16)a.z, (_Float16)a.w};
                f.hv[2] = (h2v){(_Float16)b.x, (_Float16)b.y};
                f.hv[3] = (h2v){(_Float16)b.z, (_Float16)b.w};
                w[v] = f.u;
            }
            uint4* dst = (uint4*)&Hst[row * PPAD + cb];
            #pragma unroll
            for (int v = 0; v < 4; ++v) dst[v] = w[v];
        }
        __syncthreads();
        #pragma unroll
        for (int rg = 0; rg < 8; ++rg) {
            FU a4[4];
            #pragma unroll
            for (int kt = 0; kt < 4; ++kt)
                a4[kt].u = *(const uint4*)&Hst[(rg * 16 + n16) * PPAD + kt * 32 + q4 * 8];
            float4v acc = (float4v){b1v, b1v, b1v, b1v};
            #pragma unroll
            for (int kt = 0; kt < 4; ++kt) {
                FU b; b.u = bw[kt];
                acc = __builtin_amdgcn_mfma_f32_16x16x32_f16(a4[kt].h8, b.h8, acc, 0, 0, 0);
            }
            const int rowb = rg * 16 + q4 * 4;
            #pragma unroll
            for (int r = 0; r < 4; ++r) {
                float z = fminf(fmaxf(acc[r], -14.f), 14.f);
                Ech[(rowb + r) * EPAD + wv * 16 + n16] = __float2half(exp2f(z));
            }
            if (wv == 0) {
                float4v qa = (float4v){0.f, 0.f, 0.f, 0.f};
                #pragma unroll
                for (int kt = 0; kt < 4; ++kt) {
                    FU b; b.u = bq[kt];
                    qa = __builtin_amdgcn_mfma_f32_16x16x32_f16(a4[kt].h8, b.h8, qa, 0, 0, 0);
                }
                if (n16 < 2) {
                    #pragma unroll
                    for (int r = 0; r < 4; ++r)
                        ((float*)&qbuf[rowb + r])[n16] = qa[r];
                }
            }
        }
        __syncthreads();
        // waves 2c, 2c+1 pull their rows into registers (Ech reads race-free:
        // next chunk's writes are behind the next stage barrier)
        if ((wv >> 1) == c) {
            const int lr = (wv & 1) * 64 + lane;
            #pragma unroll
            for (int u = 0; u < 16; ++u) {
                hwr[u] = *(const uint4*)&Ech[lr * EPAD + u * 8];
                LAUNDER4(hwr[u]);
            }
            float2 t = qbuf[lr];
            qv = t.x; rv = t.y;
        }
    }
    __syncthreads();
    __builtin_amdgcn_sched_barrier(0);

    // ==== init phase 2: persistent W-frags from global (L2-resident) ====
    // w1f: frag fi = wv*8+kt (KK*W1[0:256]); wtf: fi = wv*16+q2 (Whh^T)
    uint4 w1f[8];
    #pragma unroll
    for (int kt = 0; kt < 8; ++kt) {
        FU f;
        #pragma unroll
        for (int j = 0; j < 8; ++j) {
            int row = kt * 32 + q4 * 8 + j;
            f.f16[j] = (_Float16)(KK * W1[row * 128 + wv * 16 + n16]);
        }
        w1f[kt] = f.u;
        LAUNDER4(w1f[kt]);
    }
    uint4 wtf[16];
    #pragma unroll
    for (int q2 = 0; q2 < 16; ++q2) {
        const int nt = wv * 4 + (q2 >> 2), ktq = q2 & 3;
        FU f;
        #pragma unroll
        for (int j = 0; j < 8; ++j) {
            int k = ktq * 32 + q4 * 8 + j;
            f.f16[j] = (_Float16)(Whh[(nt * 16 + n16) * 128 + k]);
        }
        wtf[q2] = f.u;
        LAUNDER4(wtf[q2]);
    }
    __builtin_amdgcn_sched_barrier(0);

    // ==== init phase 3: persistent LDS + scalars ====
    ((unsigned*)sm.dc)[tid] = 0u;
    ((unsigned*)sm.dc)[512 + tid] = 0u;
    if (tid < 128) sm.w2h[tid] = __float2half(-KK * W2[tid]);  // 2*log2e*W2
    sm.sY[tid] = Y[(long)bbase * TN + tid];
    float c0 = 0.f, c1 = 0.f;
    float dAr = 0.f, dBr = 0.f;        // final-step d (epilogue)
    float ctxc = 0.f;                  // final-step ctx.fcfW[128:256] (scalar)
    float wihA[4], wihB[4], bsA[4], bsB[4];
    #pragma unroll
    for (int q = 0; q < 4; ++q) {
        wihA[q] = Wih[q * 128 + lane];
        wihB[q] = Wih[q * 128 + 64 + lane];
        bsA[q] = bih[q * 128 + lane] + bhh[q * 128 + lane];
        bsB[q] = bih[q * 128 + 64 + lane] + bhh[q * 128 + 64 + lane];
    }
    const float fcw2 = fcW[128], fcb0 = fcb[0];
    __syncthreads();

    // ==== scan loop: byte-identical to the verified R10 structure ====
    #pragma unroll 1
    for (int s = 0; s < TN; ++s) {
        // region A: p + gates MFMAs; all frag regs die before b1 (R5 lesson)
        {
            const int m = lane & 15, q = lane >> 4;
            FU a4[4];
            #pragma unroll
            for (int kt = 0; kt < 4; ++kt) {
                int slot = ((kt * 4 + q) & 15) ^ m;      // d-part chunks
                a4[kt].u = *(const uint4*)&sm.dc[m * 256 + slot * 8];
            }
            float4v pacc1 = (float4v){0.f, 0.f, 0.f, 0.f};
            float4v pacc2 = (float4v){0.f, 0.f, 0.f, 0.f};
            float4v gacc[4];
            #pragma unroll
            for (int i = 0; i < 4; ++i) gacc[i] = (float4v){0.f, 0.f, 0.f, 0.f};
            #pragma unroll
            for (int kt = 0; kt < 4; ++kt) {
                FU b; b.u = w1f[kt];
                pacc1 = __builtin_amdgcn_mfma_f32_16x16x32_f16(a4[kt].h8, b.h8, pacc1, 0, 0, 0);
            }
            #pragma unroll
            for (int i = 0; i < 4; ++i) {
                #pragma unroll
                for (int kt = 0; kt < 4; ++kt) {
                    FU b; b.u = wtf[i * 4 + kt];
                    gacc[i] = __builtin_amdgcn_mfma_f32_16x16x32_f16(a4[kt].h8, b.h8, gacc[i], 0, 0, 0);
                }
            }
            #pragma unroll
            for (int kt = 0; kt < 4; ++kt) {
                int slot = 16 | (((kt * 4 + q) & 15) ^ m);   // c-part chunks
                FU a; a.u = *(const uint4*)&sm.dc[m * 256 + slot * 8];
                FU b; b.u = w1f[4 + kt];
                pacc2 = __builtin_amdgcn_mfma_f32_16x16x32_f16(a.h8, b.h8, pacc2, 0, 0, 0);
            }
            if (lane < 32) {
                const int row0 = (lane >> 4) * 4, col = lane & 15;
                #pragma unroll
                for (int r = 0; r < 4; ++r) {
                    float pv = fminf(fmaxf(pacc1[r] + pacc2[r], -14.f), 14.f);
                    sm.spH[(row0 + r) * 128 + wv * 16 + col] = __float2half(exp2f(pv));
                }
                #pragma unroll
                for (int i = 0; i < 4; ++i) {
                    #pragma unroll
                    for (int r = 0; r < 4; ++r)
                        sm.sg[(row0 + r) * 512 + (wv * 4 + i) * 16 + col] = gacc[i][r];
                }
            }
        }
        __syncthreads();   // b1

        // phase 3: wave-local: e -> softmax sums -> y~ -> LSTM
        {
            const uint4* pH = (const uint4*)&sm.spH[g * 128];
            const __half2* w2b = (const __half2*)sm.w2h;
            const __half2 one2 = __float2half2_rn(1.f);
            float ea0 = 0.f, ea1 = 0.f, ea2 = 0.f, ea3 = 0.f;
            #pragma unroll
            for (int u = 0; u < 16; ++u) {
                FU hw; hw.u = hwr[u];
                FU pp; pp.u = pH[u];
                __half2 th0 = h2rcp(__hfma2(hw.h2[0], pp.h2[0], one2));
                __half2 th1 = h2rcp(__hfma2(hw.h2[1], pp.h2[1], one2));
                __half2 th2 = h2rcp(__hfma2(hw.h2[2], pp.h2[2], one2));
                __half2 th3 = h2rcp(__hfma2(hw.h2[3], pp.h2[3], one2));
                ea0 = fdot2f(th0, w2b[u * 4 + 0], ea0);
                ea1 = fdot2f(th1, w2b[u * 4 + 1], ea1);
                ea2 = fdot2f(th2, w2b[u * 4 + 2], ea2);
                ea3 = fdot2f(th3, w2b[u * 4 + 3], ea3);
            }
            float ea = (ea0 + ea1) + (ea2 + ea3);
            float ex = exp2f(ea);
            float ssum = wave_sum64(ex);
            float sq = wave_sum64(ex * qv);
            float rs = __builtin_amdgcn_rcpf(ssum);
            if (s == TN - 1)
                ctxc = wave_sum64(ex * rv) * rs;       // epilogue ctx.fcfW part
            float syg = fmaf(sq, rs, fmaf(sm.sY[g * 64 + s], fcw2, fcb0));
            float a0A = sm.sg[g * 512 + lane]       + fmaf(syg, wihA[0], bsA[0]);
            float a1A = sm.sg[g * 512 + 128 + lane] + fmaf(syg, wihA[1], bsA[1]);
            float a2A = sm.sg[g * 512 + 256 + lane] + fmaf(syg, wihA[2], bsA[2]);
            float a3A = sm.sg[g * 512 + 384 + lane] + fmaf(syg, wihA[3], bsA[3]);
            float a0B = sm.sg[g * 512 + 64 + lane]  + fmaf(syg, wihB[0], bsB[0]);
            float a1B = sm.sg[g * 512 + 192 + lane] + fmaf(syg, wihB[1], bsB[1]);
            float a2B = sm.sg[g * 512 + 320 + lane] + fmaf(syg, wihB[2], bsB[2]);
            float a3B = sm.sg[g * 512 + 448 + lane] + fmaf(syg, wihB[3], bsB[3]);
            float iA = fast_sigmoid(a0A), fA = fast_sigmoid(a1A);
            float gA = fast_tanhf(a2A),  oA = fast_sigmoid(a3A);
            c0 = fmaf(fA, c0, iA * gA);
            dAr = oA * fast_tanhf(c0);
            float iB = fast_sigmoid(a0B), fB = fast_sigmoid(a1B);
            float gB = fast_tanhf(a2B),  oB = fast_sigmoid(a3B);
            c1 = fmaf(fB, c1, iB * gB);
            dBr = oB * fast_tanhf(c1);
            sm.dc[dc_off(g, lane)] = __float2half(dAr);
            sm.dc[dc_off(g, 64 + lane)] = __float2half(dBr);
            sm.dc[dc_off(g, 128 + lane)] = __float2half(c0);
            sm.dc[dc_off(g, 192 + lane)] = __float2half(c1);
        }
        __syncthreads();   // b2 (step end)
    }

    // ---- epilogue: d from registers (fp32), ctx part via in-block r ----
    {
        float part = dAr * fcfW[lane] + dBr * fcfW[64 + lane];
        float tot = wave_sum64(part);
        if (lane == 0) out[bbase + g] = tot + ctxc + fcfb[0];
    }
}

extern "C" void kernel_launch(void* const* d_in, const int* in_sizes, int n_in,
                              void* d_out, int out_size, void* d_ws, size_t ws_size,
                              hipStream_t stream) {
    const float* H    = (const float*)d_in[0];
    const float* Y    = (const float*)d_in[1];
    const float* W1   = (const float*)d_in[2];
    const float* b1   = (const float*)d_in[3];
    const float* W2   = (const float*)d_in[4];
    // d_in[5] = attn_b2: softmax-shift-invariant, unused
    const float* Wih  = (const float*)d_in[6];
    const float* Whh  = (const float*)d_in[7];
    const float* bih  = (const float*)d_in[8];
    const float* bhh  = (const float*)d_in[9];
    const float* fcW  = (const float*)d_in[10];
    const float* fcb  = (const float*)d_in[11];
    const float* fcfW = (const float*)d_in[12];
    const float* fcfb = (const float*)d_in[13];
    float* out = (float*)d_out;

    decoder_scan<<<NBLK, 512, 0, stream>>>(H, Y, W1, b1, W2, Wih, Whh,
                                           bih, bhh, fcW, fcb, fcfW, fcfb, out);
}